// Round 3
// baseline (4323.805 us; speedup 1.0000x reference)
//
#include <hip/hip_runtime.h>
#include <math.h>

// Problem constants (from reference)
#define NPTS     16384
#define KNN_K    40
#define KNN_CAP  448   // per-row survivor buffer (u32 keys); soft-compact keeps it safe
#define SOFT_CAP 320   // compact when count exceeds this at a chunk boundary

// ---- bf16 (stored as ushort bits) helpers: fp32 compute, bf16 storage -----
static __device__ __forceinline__ float bf2f(unsigned short h) {
  return __uint_as_float(((unsigned)h) << 16);
}
static __device__ __forceinline__ unsigned short f2bf(float f) {
  unsigned u = __float_as_uint(f);
  unsigned r = (u + 0x7fffu + ((u >> 16) & 1u)) >> 16;   // round-nearest-even
  return (unsigned short)r;
}
static __device__ __forceinline__ float ldf(const float* p) { return *p; }
static __device__ __forceinline__ float ldf(const unsigned short* p) { return bf2f(*p); }

static __device__ __forceinline__ float rfl(float x) {   // readfirstlane -> SGPR
  return __uint_as_float(__builtin_amdgcn_readfirstlane(__float_as_uint(x)));
}
static __device__ __forceinline__ unsigned mbcnt64(unsigned long long m) {
  return __builtin_amdgcn_mbcnt_hi((unsigned)(m >> 32),
                                   __builtin_amdgcn_mbcnt_lo((unsigned)m, 0u));
}

// ---------------------------------------------------------------------------
// Generic fused GEMM: C[N x MCOLS] = (relu?)(concat(A1[:, :K1], A2[:, K1:K]) @ W + bias)
// ---------------------------------------------------------------------------
template<int MCOLS, bool RELU, typename TIN, typename TOUT>
__global__ __launch_bounds__(256, 4) void gemm_k(
    const TIN* __restrict__ A1, int lda1,
    const TIN* __restrict__ A2, int lda2, int K1,
    const float* __restrict__ W, const float* __restrict__ bias,
    TOUT* __restrict__ C, int ldc, int K)
{
  constexpr int TCS = MCOLS / 8;
  constexpr int RPT = (64 * TCS) / 256;
  __shared__ float As[64][33];
  __shared__ float Ws[32][MCOLS];
  const int tid = threadIdx.x;
  const int row0 = blockIdx.x * 64;
  const int tc = tid % TCS, tr = tid / TCS;

  float acc[RPT][8];
  #pragma unroll
  for (int p = 0; p < RPT; ++p)
    #pragma unroll
    for (int q = 0; q < 8; ++q) acc[p][q] = 0.f;

  for (int k0 = 0; k0 < K; k0 += 32) {
    __syncthreads();
    for (int l = tid; l < 64 * 32; l += 256) {
      int r = l >> 5, c = l & 31, k = k0 + c;
      float v = 0.f;
      if (k < K) v = (k < K1) ? ldf(&A1[(size_t)(row0 + r) * lda1 + k])
                              : ldf(&A2[(size_t)(row0 + r) * lda2 + (k - K1)]);
      As[r][c] = v;
    }
    for (int l = tid; l < 32 * MCOLS; l += 256) {
      int kr = l / MCOLS, c = l % MCOLS, k = k0 + kr;
      Ws[kr][c] = (k < K) ? W[(size_t)k * MCOLS + c] : 0.f;
    }
    __syncthreads();
    #pragma unroll
    for (int kk = 0; kk < 32; ++kk) {
      float a[RPT];
      #pragma unroll
      for (int p = 0; p < RPT; ++p) a[p] = As[tr * RPT + p][kk];
      const float4 w0 = *(const float4*)&Ws[kk][tc * 8];
      const float4 w1 = *(const float4*)&Ws[kk][tc * 8 + 4];
      #pragma unroll
      for (int p = 0; p < RPT; ++p) {
        acc[p][0] = fmaf(a[p], w0.x, acc[p][0]);
        acc[p][1] = fmaf(a[p], w0.y, acc[p][1]);
        acc[p][2] = fmaf(a[p], w0.z, acc[p][2]);
        acc[p][3] = fmaf(a[p], w0.w, acc[p][3]);
        acc[p][4] = fmaf(a[p], w1.x, acc[p][4]);
        acc[p][5] = fmaf(a[p], w1.y, acc[p][5]);
        acc[p][6] = fmaf(a[p], w1.z, acc[p][6]);
        acc[p][7] = fmaf(a[p], w1.w, acc[p][7]);
      }
    }
  }

  const float4 b0 = *(const float4*)&bias[tc * 8];
  const float4 b1 = *(const float4*)&bias[tc * 8 + 4];
  #pragma unroll
  for (int p = 0; p < RPT; ++p) {
    int r = row0 + tr * RPT + p;
    float o[8];
    o[0] = acc[p][0] + b0.x; o[1] = acc[p][1] + b0.y;
    o[2] = acc[p][2] + b0.z; o[3] = acc[p][3] + b0.w;
    o[4] = acc[p][4] + b1.x; o[5] = acc[p][5] + b1.y;
    o[6] = acc[p][6] + b1.z; o[7] = acc[p][7] + b1.w;
    if (RELU) {
      #pragma unroll
      for (int q = 0; q < 8; ++q) o[q] = fmaxf(o[q], 0.f);
    }
    if constexpr (sizeof(TOUT) == 2) {
      unsigned p0 = (unsigned)f2bf(o[0]) | ((unsigned)f2bf(o[1]) << 16);
      unsigned p1 = (unsigned)f2bf(o[2]) | ((unsigned)f2bf(o[3]) << 16);
      unsigned p2 = (unsigned)f2bf(o[4]) | ((unsigned)f2bf(o[5]) << 16);
      unsigned p3 = (unsigned)f2bf(o[6]) | ((unsigned)f2bf(o[7]) << 16);
      uint4 pk = make_uint4(p0, p1, p2, p3);
      *(uint4*)&C[(size_t)r * ldc + tc * 8] = pk;
    } else {
      float4 o0, o1;
      o0.x = o[0]; o0.y = o[1]; o0.z = o[2]; o0.w = o[3];
      o1.x = o[4]; o1.y = o[5]; o1.z = o[6]; o1.w = o[7];
      *(float4*)&C[(size_t)r * ldc + tc * 8] = o0;
      *(float4*)&C[(size_t)r * ldc + tc * 8 + 4] = o1;
    }
  }
}

// ---------------------------------------------------------------------------
// Small-M GEMM (M = 4): lin_s and fc4.
// ---------------------------------------------------------------------------
template<bool RELU, typename TIN, typename TOUT>
__global__ __launch_bounds__(256, 2) void gemm4_k(
    const TIN* __restrict__ A, int lda,
    const float* __restrict__ W, const float* __restrict__ bias,
    TOUT* __restrict__ C, int ldc, int K)
{
  __shared__ float WsT[4][128];
  const int tid = threadIdx.x;
  for (int l = tid; l < 512; l += 256) {
    int c = l >> 7, k = l & 127;
    WsT[c][k] = (k < K) ? W[k * 4 + c] : 0.f;
  }
  __syncthreads();
  const int row = blockIdx.x * 64 + (tid >> 2);
  const int c = tid & 3;
  const TIN* ap = A + (size_t)row * lda;
  float acc = 0.f;
  for (int k = 0; k < K; ++k) acc = fmaf(ldf(&ap[k]), WsT[c][k], acc);
  float v = acc + bias[c];
  if (RELU) v = fmaxf(v, 0.f);
  if constexpr (sizeof(TOUT) == 2) C[(size_t)row * ldc + c] = (TOUT)f2bf(v);
  else                             C[(size_t)row * ldc + c] = v;
}

// ---------------------------------------------------------------------------
// kNN v2: 2 rows/wave, 16 rows per 512-thread block. u32 keys
// (trunc18(d2) | idx14). Seed (chunks 0-1, u16-packed in 16 regs/row) gives
// threshold t0; scan appends survivors with ballot-prefix; soft-cap
// compaction re-tightens the threshold in-flight. Finalists (<=96) get exact
// d2 recomputed (bit-identical formula) and a shuffle bitonic-128 sort.
// ---------------------------------------------------------------------------
struct CompactRes { int cnt; unsigned thr; };

static __device__ CompactRes compact_buf(unsigned* bufR, int cnt, int lane) {
  int n = min(cnt, KNN_CAP);
  int lo = -1, hi = 0x7FFFFFFF, chi = n;
  for (int it = 0; it < 32; ++it) {
    if (chi <= 96) break;
    int mid = lo + ((hi - lo) >> 1);
    int lc = 0;
    for (int base = 0; base < n; base += 64) {
      int i = base + lane;
      bool c = (i < n) && (bufR[i] <= (unsigned)mid);
      lc += (int)__popcll(__ballot(c));
    }
    if (lc >= 40) { hi = mid; chi = lc; } else lo = mid;
  }
  unsigned thr = (unsigned)hi;
  int out = 0;
  for (int base = 0; base < n; base += 64) {
    int i = base + lane;
    unsigned key = (i < n) ? bufR[i] : 0xFFFFFFFFu;
    bool keep = (i < n) && (key <= thr);
    unsigned long long mk = __ballot(keep);
    unsigned pre = mbcnt64(mk);
    if (keep) bufR[out + (int)pre] = key;   // front-compaction: write idx <= read idx
    out += (int)__popcll(mk);
  }
  CompactRes r; r.cnt = out; r.thr = thr;
  return r;
}

static __device__ unsigned bisect_seed(const unsigned (&db)[16]) {
  int lo = -1, hi = 0x7F7F, chi = 2048;
  for (int it = 0; it < 20; ++it) {
    if (chi <= 41 || (hi - lo) <= 1) break;
    int mid = lo + ((hi - lo) >> 1);
    unsigned mhi = ((unsigned)mid << 16) | 0xFFFFu;
    int lc = 0;
    #pragma unroll
    for (int i = 0; i < 16; ++i) {
      lc += (int)__popcll(__ballot((db[i] & 0xFFFFu) <= (unsigned)mid));
      lc += (int)__popcll(__ballot(db[i] <= mhi));
    }
    if (lc >= 40) { hi = mid; chi = lc; } else lo = mid;
  }
  return (unsigned)hi;
}

__global__ __launch_bounds__(512, 6) void knn_k(
    const float* __restrict__ s,
    unsigned short* __restrict__ idx_out, unsigned short* __restrict__ w_out)
{
  __shared__ float4 spts[1024];
  __shared__ float  s2s[1024];
  __shared__ unsigned buf[16][KNN_CAP];

  const int tid = threadIdx.x;
  const int lane = tid & 63;
  const int w = tid >> 6;
  const int rA = blockIdx.x * 16 + w * 2;
  const int rB = rA + 1;
  const float4* s4 = (const float4*)s;

  // row constants in SGPRs: d2 = cx*px + cy*py + cz*pz + cw*pw + (s2j + s2i)
  float4 sa = s4[rA], sb = s4[rB];
  const float cAx = rfl(-2.f * sa.x), cAy = rfl(-2.f * sa.y);
  const float cAz = rfl(-2.f * sa.z), cAw = rfl(-2.f * sa.w);
  const float s2A = rfl(fmaf(sa.x, sa.x, fmaf(sa.y, sa.y, fmaf(sa.z, sa.z, sa.w * sa.w))));
  const float cBx = rfl(-2.f * sb.x), cBy = rfl(-2.f * sb.y);
  const float cBz = rfl(-2.f * sb.z), cBw = rfl(-2.f * sb.w);
  const float s2B = rfl(fmaf(sb.x, sb.x, fmaf(sb.y, sb.y, fmaf(sb.z, sb.z, sb.w * sb.w))));

  unsigned* bufA = buf[2 * w];
  unsigned* bufB = buf[2 * w + 1];

  // ---- seed: chunks 0,1 -> u16-packed d2 in registers (16/row) ----
  unsigned dbA[16], dbB[16];
  #pragma unroll
  for (int cc = 0; cc < 2; ++cc) {
    __syncthreads();
    for (int t = tid; t < 1024; t += 512) {
      float4 p = s4[cc * 1024 + t];
      spts[t] = p;
      s2s[t] = fmaf(p.x, p.x, fmaf(p.y, p.y, fmaf(p.z, p.z, p.w * p.w)));
    }
    __syncthreads();
    #pragma unroll
    for (int ii = 0; ii < 8; ++ii) {
      int j0 = (2 * ii) * 64 + lane, j1 = (2 * ii + 1) * 64 + lane;
      float4 p0 = spts[j0], p1 = spts[j1];
      float q0 = s2s[j0], q1 = s2s[j1];
      float d0A = fmaf(cAx, p0.x, fmaf(cAy, p0.y, fmaf(cAz, p0.z, fmaf(cAw, p0.w, q0 + s2A))));
      float d1A = fmaf(cAx, p1.x, fmaf(cAy, p1.y, fmaf(cAz, p1.z, fmaf(cAw, p1.w, q1 + s2A))));
      float d0B = fmaf(cBx, p0.x, fmaf(cBy, p0.y, fmaf(cBz, p0.z, fmaf(cBw, p0.w, q0 + s2B))));
      float d1B = fmaf(cBx, p1.x, fmaf(cBy, p1.y, fmaf(cBz, p1.z, fmaf(cBw, p1.w, q1 + s2B))));
      dbA[cc * 8 + ii] = (__float_as_uint(fmaxf(d0A, 0.f)) >> 16)
                       | (__float_as_uint(fmaxf(d1A, 0.f)) & 0xFFFF0000u);
      dbB[cc * 8 + ii] = (__float_as_uint(fmaxf(d0B, 0.f)) >> 16)
                       | (__float_as_uint(fmaxf(d1B, 0.f)) & 0xFFFF0000u);
    }
  }

  unsigned hA = bisect_seed(dbA);
  unsigned hB = bisect_seed(dbB);
  float t0A = __uint_as_float((hA << 16) | 0xFFFFu);
  float t0B = __uint_as_float((hB << 16) | 0xFFFFu);

  // ---- main scan: all 16 chunks, filtered ballot-prefix append ----
  int cntA = 0, cntB = 0;
  for (int c = 0; c < 16; ++c) {
    __syncthreads();
    for (int t = tid; t < 1024; t += 512) {
      float4 p = s4[c * 1024 + t];
      spts[t] = p;
      s2s[t] = fmaf(p.x, p.x, fmaf(p.y, p.y, fmaf(p.z, p.z, p.w * p.w)));
    }
    __syncthreads();
    #pragma unroll 4
    for (int i = 0; i < 16; ++i) {
      int j = i * 64 + lane;
      float4 p = spts[j];
      float q = s2s[j];
      float dA = fmaf(cAx, p.x, fmaf(cAy, p.y, fmaf(cAz, p.z, fmaf(cAw, p.w, q + s2A))));
      float dB = fmaf(cBx, p.x, fmaf(cBy, p.y, fmaf(cBz, p.z, fmaf(cBw, p.w, q + s2B))));
      unsigned gi = (unsigned)((c << 10) + (i << 6) + lane);
      bool kA = dA <= t0A;
      unsigned long long mA = __ballot(kA);
      if (mA) {
        int pos = cntA + (int)mbcnt64(mA);
        if (kA && pos < KNN_CAP)
          bufA[pos] = (__float_as_uint(fmaxf(dA, 0.f)) & 0xFFFFC000u) | gi;
        cntA += (int)__popcll(mA);
      }
      bool kB = dB <= t0B;
      unsigned long long mB = __ballot(kB);
      if (mB) {
        int pos = cntB + (int)mbcnt64(mB);
        if (kB && pos < KNN_CAP)
          bufB[pos] = (__float_as_uint(fmaxf(dB, 0.f)) & 0xFFFFC000u) | gi;
        cntB += (int)__popcll(mB);
      }
    }
    // soft-cap compaction (wave-local, no barrier)
    if (cntA > SOFT_CAP) {
      CompactRes r = compact_buf(bufA, cntA, lane);
      cntA = r.cnt; t0A = __uint_as_float(r.thr | 0x3FFFu);
    }
    if (cntB > SOFT_CAP) {
      CompactRes r = compact_buf(bufB, cntB, lane);
      cntB = r.cnt; t0B = __uint_as_float(r.thr | 0x3FFFu);
    }
  }

  if (cntA > 96) { CompactRes r = compact_buf(bufA, cntA, lane); cntA = r.cnt; }
  if (cntB > 96) { CompactRes r = compact_buf(bufB, cntB, lane); cntB = r.cnt; }

  // ---- finalists: exact d2 recompute + bitonic-128 sort + emit top-40 ----
  #pragma unroll
  for (int rr = 0; rr < 2; ++rr) {
    unsigned* bufR = rr ? bufB : bufA;
    int m = rr ? cntB : cntA;
    const float cx = rr ? cBx : cAx, cy = rr ? cBy : cAy;
    const float cz = rr ? cBz : cAz, cw = rr ? cBw : cAw;
    const float s2i = rr ? s2B : s2A;
    const int row = rr ? rB : rA;

    unsigned long long e0 = ~0ull, e1 = ~0ull;
    {
      int sl0 = lane * 2, sl1 = lane * 2 + 1;
      if (sl0 < m) {
        unsigned key = bufR[sl0];
        unsigned idx = key & 0x3FFFu;
        float4 p = s4[idx];
        float qj = fmaf(p.x, p.x, fmaf(p.y, p.y, fmaf(p.z, p.z, p.w * p.w)));
        float d = fmaf(cx, p.x, fmaf(cy, p.y, fmaf(cz, p.z, fmaf(cw, p.w, qj + s2i))));
        e0 = (((unsigned long long)__float_as_uint(fmaxf(d, 0.f))) << 32) | idx;
      }
      if (sl1 < m) {
        unsigned key = bufR[sl1];
        unsigned idx = key & 0x3FFFu;
        float4 p = s4[idx];
        float qj = fmaf(p.x, p.x, fmaf(p.y, p.y, fmaf(p.z, p.z, p.w * p.w)));
        float d = fmaf(cx, p.x, fmaf(cy, p.y, fmaf(cz, p.z, fmaf(cw, p.w, qj + s2i))));
        e1 = (((unsigned long long)__float_as_uint(fmaxf(d, 0.f))) << 32) | idx;
      }
    }

    #pragma unroll
    for (int k = 2; k <= 128; k <<= 1) {
      #pragma unroll
      for (int jj = k >> 1; jj >= 1; jj >>= 1) {
        bool up = (((lane * 2) & k) == 0);
        if (jj == 1) {
          unsigned long long a = (e0 < e1) ? e0 : e1;
          unsigned long long b = (e0 < e1) ? e1 : e0;
          e0 = up ? a : b; e1 = up ? b : a;
        } else {
          int lj = jj >> 1;
          bool lower = ((lane & lj) == 0);
          bool tm = (up == lower);
          unsigned long long o0 = __shfl_xor(e0, lj, 64);
          e0 = tm ? ((e0 < o0) ? e0 : o0) : ((e0 > o0) ? e0 : o0);
          unsigned long long o1 = __shfl_xor(e1, lj, 64);
          e1 = tm ? ((e1 < o1) ? e1 : o1) : ((e1 > o1) ? e1 : o1);
        }
      }
    }

    const int ob = row * KNN_K;
    if (lane < 20) {
      int v0 = lane * 2;
      idx_out[ob + v0] = (unsigned short)(e0 & 0xFFFFu);
      w_out[ob + v0] = f2bf(__expf(-10.f * __uint_as_float((unsigned)(e0 >> 32))));
      int v1 = v0 + 1;
      idx_out[ob + v1] = (unsigned short)(e1 & 0xFFFFu);
      w_out[ob + v1] = f2bf(__expf(-10.f * __uint_as_float((unsigned)(e1 >> 32))));
    }
  }
}

// ---------------------------------------------------------------------------
// Aggregation: Aout[i] = [mean_k h[idx]*w | max_k h[idx]*w]  (N x 128, bf16).
// ---------------------------------------------------------------------------
__global__ __launch_bounds__(256, 4) void agg_k(
    const unsigned short* __restrict__ h, const unsigned short* __restrict__ idxb,
    const unsigned short* __restrict__ wb, unsigned short* __restrict__ Aout)
{
  const int row = blockIdx.x * 4 + (threadIdx.x >> 6);
  const int lane = threadIdx.x & 63;
  const int base = row * KNN_K;
  float mean = 0.f, mx = -INFINITY;
  #pragma unroll 4
  for (int k = 0; k < KNN_K; ++k) {
    int j = idxb[base + k];
    float wv = bf2f(wb[base + k]);
    float m = bf2f(h[(size_t)j * 64 + lane]) * wv;
    mean += m;
    mx = fmaxf(mx, m);
  }
  Aout[(size_t)row * 128 + lane] = f2bf(mean * (1.f / 40.f));
  Aout[(size_t)row * 128 + 64 + lane] = f2bf(mx);
}

// ---------------------------------------------------------------------------
extern "C" void kernel_launch(void* const* d_in, const int* in_sizes, int n_in,
                              void* d_out, int out_size, void* d_ws, size_t ws_size,
                              hipStream_t stream)
{
  const float* x    = (const float*)d_in[0];
  const float* fc1W = (const float*)d_in[1];  const float* fc1b = (const float*)d_in[2];
  const float* fc2W = (const float*)d_in[3];  const float* fc2b = (const float*)d_in[4];
  const float* gsW  = (const float*)d_in[5];  const float* gsb  = (const float*)d_in[6];
  const float* ghW  = (const float*)d_in[7];  const float* ghb  = (const float*)d_in[8];
  const float* goW  = (const float*)d_in[9];  const float* gob  = (const float*)d_in[10];
  const float* d1W  = (const float*)d_in[11]; const float* d1b  = (const float*)d_in[12];
  const float* d2W  = (const float*)d_in[13]; const float* d2b  = (const float*)d_in[14];
  const float* d3W  = (const float*)d_in[15]; const float* d3b  = (const float*)d_in[16];
  const float* fc3W = (const float*)d_in[17]; const float* fc3b = (const float*)d_in[18];
  const float* fc4W = (const float*)d_in[19]; const float* fc4b = (const float*)d_in[20];
  float* out = (float*)d_out;

  // ---- workspace layout: ~14.5 MiB (bf16 activations, u16 idx) ----
  const size_t N = NPTS;
  unsigned short* X    = (unsigned short*)d_ws;
  unsigned short* Abuf = X + N * 128;
  unsigned short* T    = Abuf + N * 128;
  unsigned short* IDX  = T + N * 128;
  unsigned short* WNB  = IDX + N * 40;
  float* S = (float*)Abuf;        // N*4 fp32 aliased at start of Abuf
  unsigned short* H = T;          // N*64 bf16 aliased at start of T

  typedef unsigned short u16;

  gemm_k<128, true, float, u16><<<NPTS / 64, 256, 0, stream>>>(
      x, 9, x, 9, 9, fc1W, fc1b, T, 128, 9);
  gemm_k<128, true, u16, u16><<<NPTS / 64, 256, 0, stream>>>(
      T, 128, T, 128, 128, fc2W, fc2b, X, 128, 128);

  for (int l = 0; l < 4; ++l) {
    gemm4_k<false, u16, float><<<NPTS / 64, 256, 0, stream>>>(
        X, 128, gsW + l * 128 * 4, gsb + l * 4, S, 4, 128);
    gemm_k<64, false, u16, u16><<<NPTS / 64, 256, 0, stream>>>(
        X, 128, X, 128, 128, ghW + l * 128 * 64, ghb + l * 64, H, 64, 128);
    knn_k<<<NPTS / 16, 512, 0, stream>>>(S, IDX, WNB);
    agg_k<<<NPTS / 4, 256, 0, stream>>>(H, IDX, WNB, Abuf);
    gemm_k<128, false, u16, u16><<<NPTS / 64, 256, 0, stream>>>(
        X, 128, Abuf, 128, 128, goW + l * 256 * 128, gob + l * 128, T, 128, 256);
    gemm_k<128, true, u16, u16><<<NPTS / 64, 256, 0, stream>>>(
        T, 128, T, 128, 128, d1W + l * 128 * 128, d1b + l * 128, Abuf, 128, 128);
    gemm_k<128, true, u16, u16><<<NPTS / 64, 256, 0, stream>>>(
        Abuf, 128, Abuf, 128, 128, d2W + l * 128 * 128, d2b + l * 128, T, 128, 128);
    gemm_k<128, true, u16, u16><<<NPTS / 64, 256, 0, stream>>>(
        T, 128, T, 128, 128, d3W + l * 128 * 128, d3b + l * 128, X, 128, 128);
  }

  gemm_k<128, true, u16, u16><<<NPTS / 64, 256, 0, stream>>>(
      X, 128, X, 128, 128, fc3W, fc3b, T, 128, 128);
  gemm4_k<false, u16, float><<<NPTS / 64, 256, 0, stream>>>(
      T, 128, fc4W, fc4b, out, 4, 128);
}

// Round 4
// 4183.983 us; speedup vs baseline: 1.0334x; 1.0334x over previous
//
#include <hip/hip_runtime.h>
#include <math.h>

// Problem constants (from reference)
#define NPTS     16384
#define KNN_K    40
#define KNN_CAP  448   // per-row survivor buffer (u32 keys); soft-compact keeps it safe
#define SOFT_CAP 320   // compact when count exceeds this at a chunk boundary

typedef unsigned short u16;
typedef __attribute__((ext_vector_type(8))) short bf16x8;
typedef __attribute__((ext_vector_type(4))) float f32x4;

// ---- bf16 (stored as ushort bits) helpers: fp32 compute, bf16 storage -----
static __device__ __forceinline__ float bf2f(unsigned short h) {
  return __uint_as_float(((unsigned)h) << 16);
}
static __device__ __forceinline__ unsigned short f2bf(float f) {
  unsigned u = __float_as_uint(f);
  unsigned r = (u + 0x7fffu + ((u >> 16) & 1u)) >> 16;   // round-nearest-even
  return (unsigned short)r;
}
static __device__ __forceinline__ float ldf(const float* p) { return *p; }
static __device__ __forceinline__ float ldf(const unsigned short* p) { return bf2f(*p); }

static __device__ __forceinline__ float rfl(float x) {   // readfirstlane -> SGPR
  return __uint_as_float(__builtin_amdgcn_readfirstlane(__float_as_uint(x)));
}
static __device__ __forceinline__ unsigned mbcnt64(unsigned long long m) {
  return __builtin_amdgcn_mbcnt_hi((unsigned)(m >> 32),
                                   __builtin_amdgcn_mbcnt_lo((unsigned)m, 0u));
}

// ---------------------------------------------------------------------------
// MFMA GEMM: C[N x MCOLS] = (relu?)(concat(A1,A2) @ W + bias), bf16 in/out,
// fp32 weights split hi/lo bf16 (W = Whi + Wlo) -> two chained MFMAs keep
// effective weight precision ~2^-18 (accuracy stays activation-bf16-bound).
// 64-row x MCOLS tile per block, 256 thr = 4 waves; K staged in 32-chunks.
// ---------------------------------------------------------------------------
template<int MCOLS, bool RELU>
__global__ __launch_bounds__(256, 2) void gemm_mfma_k(
    const u16* __restrict__ A1, int lda1,
    const u16* __restrict__ A2, int lda2, int K1,
    const float* __restrict__ W, const float* __restrict__ bias,
    u16* __restrict__ C, int ldc, int K)
{
  constexpr int CT = MCOLS / 64;      // 16-col tiles per wave (128->2, 64->1)
  constexpr int AST = 40;             // LDS row stride (32 k + 8 pad), 16B-aligned
  __shared__ u16 lds[64 * AST + 2 * MCOLS * AST];
  u16* As = lds;
  u16* Wh = lds + 64 * AST;
  u16* Wl = Wh + MCOLS * AST;

  const int tid = threadIdx.x;
  const int lane = tid & 63;
  const int w = tid >> 6;
  const int row0 = blockIdx.x * 64;

  f32x4 acc[4][CT];
  #pragma unroll
  for (int rt = 0; rt < 4; ++rt)
    #pragma unroll
    for (int ct = 0; ct < CT; ++ct)
      acc[rt][ct] = (f32x4){0.f, 0.f, 0.f, 0.f};

  const int rbase = lane & 15;
  const int koff = (lane >> 4) * 8;

  for (int k0 = 0; k0 < K; k0 += 32) {
    __syncthreads();
    // stage A tile 64 x 32 (16B per thread; concat source never straddles K1)
    {
      int r = tid >> 2, seg = tid & 3;
      int kk = k0 + seg * 8;
      const u16* src = (kk < K1) ? &A1[(size_t)(row0 + r) * lda1 + kk]
                                 : &A2[(size_t)(row0 + r) * lda2 + (kk - K1)];
      *(uint4*)&As[r * AST + seg * 8] = *(const uint4*)src;
    }
    // stage W chunk 32 x MCOLS, transposed + hi/lo split
    for (int l = tid; l < 32 * MCOLS; l += 256) {
      int n = l & (MCOLS - 1), kk = l / MCOLS;
      float wv = W[(size_t)(k0 + kk) * MCOLS + n];
      u16 h = f2bf(wv);
      Wh[n * AST + kk] = h;
      Wl[n * AST + kk] = f2bf(wv - bf2f(h));
    }
    __syncthreads();

    bf16x8 a[4];
    #pragma unroll
    for (int rt = 0; rt < 4; ++rt)
      a[rt] = *(const bf16x8*)&As[(rt * 16 + rbase) * AST + koff];
    #pragma unroll
    for (int ct = 0; ct < CT; ++ct) {
      int col = (w * CT + ct) * 16 + rbase;
      bf16x8 bh = *(const bf16x8*)&Wh[col * AST + koff];
      bf16x8 bl = *(const bf16x8*)&Wl[col * AST + koff];
      #pragma unroll
      for (int rt = 0; rt < 4; ++rt) {
        acc[rt][ct] = __builtin_amdgcn_mfma_f32_16x16x32_bf16(a[rt], bh, acc[rt][ct], 0, 0, 0);
        acc[rt][ct] = __builtin_amdgcn_mfma_f32_16x16x32_bf16(a[rt], bl, acc[rt][ct], 0, 0, 0);
      }
    }
  }

  // epilogue: bias + relu, bf16 pack via LDS for coalesced stores
  __syncthreads();
  constexpr int CST = MCOLS + 8;
  u16* Ct = lds;
  const int rq = (lane >> 4) * 4;
  #pragma unroll
  for (int ct = 0; ct < CT; ++ct) {
    int col = (w * CT + ct) * 16 + rbase;
    float bv = bias[col];
    #pragma unroll
    for (int rt = 0; rt < 4; ++rt) {
      #pragma unroll
      for (int q = 0; q < 4; ++q) {
        float v = acc[rt][ct][q] + bv;
        if (RELU) v = fmaxf(v, 0.f);
        Ct[(rt * 16 + rq + q) * CST + col] = f2bf(v);
      }
    }
  }
  __syncthreads();
  constexpr int SEGS = MCOLS / 8;
  for (int l = tid; l < 64 * SEGS; l += 256) {
    int r = l / SEGS, sg = l % SEGS;
    *(uint4*)&C[(size_t)(row0 + r) * ldc + sg * 8] = *(const uint4*)&Ct[r * CST + sg * 8];
  }
}

// ---------------------------------------------------------------------------
// VALU GEMM (fc1 only: K=9, fp32 input)
// ---------------------------------------------------------------------------
template<int MCOLS, bool RELU, typename TIN, typename TOUT>
__global__ __launch_bounds__(256, 4) void gemm_k(
    const TIN* __restrict__ A1, int lda1,
    const TIN* __restrict__ A2, int lda2, int K1,
    const float* __restrict__ W, const float* __restrict__ bias,
    TOUT* __restrict__ C, int ldc, int K)
{
  constexpr int TCS = MCOLS / 8;
  constexpr int RPT = (64 * TCS) / 256;
  __shared__ float Asl[64][33];
  __shared__ float Ws[32][MCOLS];
  const int tid = threadIdx.x;
  const int row0 = blockIdx.x * 64;
  const int tc = tid % TCS, tr = tid / TCS;

  float acc[RPT][8];
  #pragma unroll
  for (int p = 0; p < RPT; ++p)
    #pragma unroll
    for (int q = 0; q < 8; ++q) acc[p][q] = 0.f;

  for (int k0 = 0; k0 < K; k0 += 32) {
    __syncthreads();
    for (int l = tid; l < 64 * 32; l += 256) {
      int r = l >> 5, c = l & 31, k = k0 + c;
      float v = 0.f;
      if (k < K) v = (k < K1) ? ldf(&A1[(size_t)(row0 + r) * lda1 + k])
                              : ldf(&A2[(size_t)(row0 + r) * lda2 + (k - K1)]);
      Asl[r][c] = v;
    }
    for (int l = tid; l < 32 * MCOLS; l += 256) {
      int kr = l / MCOLS, c = l % MCOLS, k = k0 + kr;
      Ws[kr][c] = (k < K) ? W[(size_t)k * MCOLS + c] : 0.f;
    }
    __syncthreads();
    #pragma unroll
    for (int kk = 0; kk < 32; ++kk) {
      float a[RPT];
      #pragma unroll
      for (int p = 0; p < RPT; ++p) a[p] = Asl[tr * RPT + p][kk];
      const float4 w0 = *(const float4*)&Ws[kk][tc * 8];
      const float4 w1 = *(const float4*)&Ws[kk][tc * 8 + 4];
      #pragma unroll
      for (int p = 0; p < RPT; ++p) {
        acc[p][0] = fmaf(a[p], w0.x, acc[p][0]);
        acc[p][1] = fmaf(a[p], w0.y, acc[p][1]);
        acc[p][2] = fmaf(a[p], w0.z, acc[p][2]);
        acc[p][3] = fmaf(a[p], w0.w, acc[p][3]);
        acc[p][4] = fmaf(a[p], w1.x, acc[p][4]);
        acc[p][5] = fmaf(a[p], w1.y, acc[p][5]);
        acc[p][6] = fmaf(a[p], w1.z, acc[p][6]);
        acc[p][7] = fmaf(a[p], w1.w, acc[p][7]);
      }
    }
  }

  const float4 b0 = *(const float4*)&bias[tc * 8];
  const float4 b1 = *(const float4*)&bias[tc * 8 + 4];
  #pragma unroll
  for (int p = 0; p < RPT; ++p) {
    int r = row0 + tr * RPT + p;
    float o[8];
    o[0] = acc[p][0] + b0.x; o[1] = acc[p][1] + b0.y;
    o[2] = acc[p][2] + b0.z; o[3] = acc[p][3] + b0.w;
    o[4] = acc[p][4] + b1.x; o[5] = acc[p][5] + b1.y;
    o[6] = acc[p][6] + b1.z; o[7] = acc[p][7] + b1.w;
    if (RELU) {
      #pragma unroll
      for (int q = 0; q < 8; ++q) o[q] = fmaxf(o[q], 0.f);
    }
    if constexpr (sizeof(TOUT) == 2) {
      unsigned p0 = (unsigned)f2bf(o[0]) | ((unsigned)f2bf(o[1]) << 16);
      unsigned p1 = (unsigned)f2bf(o[2]) | ((unsigned)f2bf(o[3]) << 16);
      unsigned p2 = (unsigned)f2bf(o[4]) | ((unsigned)f2bf(o[5]) << 16);
      unsigned p3 = (unsigned)f2bf(o[6]) | ((unsigned)f2bf(o[7]) << 16);
      uint4 pk = make_uint4(p0, p1, p2, p3);
      *(uint4*)&C[(size_t)r * ldc + tc * 8] = pk;
    } else {
      float4 o0, o1;
      o0.x = o[0]; o0.y = o[1]; o0.z = o[2]; o0.w = o[3];
      o1.x = o[4]; o1.y = o[5]; o1.z = o[6]; o1.w = o[7];
      *(float4*)&C[(size_t)r * ldc + tc * 8] = o0;
      *(float4*)&C[(size_t)r * ldc + tc * 8 + 4] = o1;
    }
  }
}

// ---------------------------------------------------------------------------
// Small-M GEMM (M = 4): lin_s and fc4. One thread per row, bf16 input.
// ---------------------------------------------------------------------------
template<bool RELU, typename TOUT>
__global__ __launch_bounds__(256, 4) void gemm4_k(
    const u16* __restrict__ A, int lda,
    const float* __restrict__ W, const float* __restrict__ bias,
    TOUT* __restrict__ C, int K)
{
  __shared__ float Wsl[128 * 4];
  __shared__ float bl[4];
  const int tid = threadIdx.x;
  for (int l = tid; l < K * 4; l += 256) Wsl[l] = W[l];
  if (tid < 4) bl[tid] = bias[tid];
  __syncthreads();
  const int row = blockIdx.x * 256 + tid;
  const u16* ap = A + (size_t)row * lda;
  float a0 = bl[0], a1 = bl[1], a2 = bl[2], a3 = bl[3];
  for (int k8 = 0; k8 < K; k8 += 8) {
    uint4 pk = *(const uint4*)&ap[k8];
    unsigned uu[4] = {pk.x, pk.y, pk.z, pk.w};
    #pragma unroll
    for (int q = 0; q < 4; ++q) {
      float flo = __uint_as_float(uu[q] << 16);
      float fhi = __uint_as_float(uu[q] & 0xFFFF0000u);
      const float* wr0 = &Wsl[(k8 + 2 * q) * 4];
      a0 = fmaf(flo, wr0[0], a0); a1 = fmaf(flo, wr0[1], a1);
      a2 = fmaf(flo, wr0[2], a2); a3 = fmaf(flo, wr0[3], a3);
      a0 = fmaf(fhi, wr0[4], a0); a1 = fmaf(fhi, wr0[5], a1);
      a2 = fmaf(fhi, wr0[6], a2); a3 = fmaf(fhi, wr0[7], a3);
    }
  }
  if (RELU) {
    a0 = fmaxf(a0, 0.f); a1 = fmaxf(a1, 0.f);
    a2 = fmaxf(a2, 0.f); a3 = fmaxf(a3, 0.f);
  }
  if constexpr (sizeof(TOUT) == 2) {
    C[(size_t)row * 4 + 0] = (TOUT)f2bf(a0);
    C[(size_t)row * 4 + 1] = (TOUT)f2bf(a1);
    C[(size_t)row * 4 + 2] = (TOUT)f2bf(a2);
    C[(size_t)row * 4 + 3] = (TOUT)f2bf(a3);
  } else {
    float4 o; o.x = a0; o.y = a1; o.z = a2; o.w = a3;
    *(float4*)&C[(size_t)row * 4] = o;
  }
}

// ---------------------------------------------------------------------------
// kNN v2 (spill-fixed): 2 rows/wave, 16 rows per 512-thread block. u32 keys
// (trunc18(d2) | idx14). Seed (chunks 0-1, u16-packed) -> threshold t0;
// filtered ballot-prefix append; soft-cap compaction; exact finalist
// recompute + bitonic-128 sort. __launch_bounds__(512,4): 128-VGPR budget,
// NO spilling (the (512,6) variant spilled the seed arrays -> 224 MB HBM).
// ---------------------------------------------------------------------------
struct CompactRes { int cnt; unsigned thr; };

static __device__ CompactRes compact_buf(unsigned* bufR, int cnt, int lane) {
  int n = min(cnt, KNN_CAP);
  int lo = -1, hi = 0x7FFFFFFF, chi = n;
  for (int it = 0; it < 32; ++it) {
    if (chi <= 96) break;
    int mid = lo + ((hi - lo) >> 1);
    int lc = 0;
    for (int base = 0; base < n; base += 64) {
      int i = base + lane;
      bool c = (i < n) && (bufR[i] <= (unsigned)mid);
      lc += (int)__popcll(__ballot(c));
    }
    if (lc >= 40) { hi = mid; chi = lc; } else lo = mid;
  }
  unsigned thr = (unsigned)hi;
  int out = 0;
  for (int base = 0; base < n; base += 64) {
    int i = base + lane;
    unsigned key = (i < n) ? bufR[i] : 0xFFFFFFFFu;
    bool keep = (i < n) && (key <= thr);
    unsigned long long mk = __ballot(keep);
    unsigned pre = mbcnt64(mk);
    if (keep) bufR[out + (int)pre] = key;   // front-compaction: write idx <= read idx
    out += (int)__popcll(mk);
  }
  CompactRes r; r.cnt = out; r.thr = thr;
  return r;
}

static __device__ unsigned bisect_seed(const unsigned (&db)[16]) {
  int lo = -1, hi = 0x7F7F, chi = 2048;
  for (int it = 0; it < 20; ++it) {
    if (chi <= 41 || (hi - lo) <= 1) break;
    int mid = lo + ((hi - lo) >> 1);
    unsigned mhi = ((unsigned)mid << 16) | 0xFFFFu;
    int lc = 0;
    #pragma unroll
    for (int i = 0; i < 16; ++i) {
      lc += (int)__popcll(__ballot((db[i] & 0xFFFFu) <= (unsigned)mid));
      lc += (int)__popcll(__ballot(db[i] <= mhi));
    }
    if (lc >= 40) { hi = mid; chi = lc; } else lo = mid;
  }
  return (unsigned)hi;
}

__global__ __launch_bounds__(512, 4) void knn_k(
    const float* __restrict__ s,
    unsigned short* __restrict__ idx_out, unsigned short* __restrict__ w_out)
{
  __shared__ float4 spts[1024];
  __shared__ float  s2s[1024];
  __shared__ unsigned buf[16][KNN_CAP];

  const int tid = threadIdx.x;
  const int lane = tid & 63;
  const int w = tid >> 6;
  const int rA = blockIdx.x * 16 + w * 2;
  const int rB = rA + 1;
  const float4* s4 = (const float4*)s;

  float4 sa = s4[rA], sb = s4[rB];
  const float cAx = rfl(-2.f * sa.x), cAy = rfl(-2.f * sa.y);
  const float cAz = rfl(-2.f * sa.z), cAw = rfl(-2.f * sa.w);
  const float s2A = rfl(fmaf(sa.x, sa.x, fmaf(sa.y, sa.y, fmaf(sa.z, sa.z, sa.w * sa.w))));
  const float cBx = rfl(-2.f * sb.x), cBy = rfl(-2.f * sb.y);
  const float cBz = rfl(-2.f * sb.z), cBw = rfl(-2.f * sb.w);
  const float s2B = rfl(fmaf(sb.x, sb.x, fmaf(sb.y, sb.y, fmaf(sb.z, sb.z, sb.w * sb.w))));

  unsigned* bufA = buf[2 * w];
  unsigned* bufB = buf[2 * w + 1];

  // ---- seed: chunks 0,1 -> u16-packed d2 in registers (16/row) ----
  unsigned dbA[16], dbB[16];
  #pragma unroll
  for (int cc = 0; cc < 2; ++cc) {
    __syncthreads();
    for (int t = tid; t < 1024; t += 512) {
      float4 p = s4[cc * 1024 + t];
      spts[t] = p;
      s2s[t] = fmaf(p.x, p.x, fmaf(p.y, p.y, fmaf(p.z, p.z, p.w * p.w)));
    }
    __syncthreads();
    #pragma unroll
    for (int ii = 0; ii < 8; ++ii) {
      int j0 = (2 * ii) * 64 + lane, j1 = (2 * ii + 1) * 64 + lane;
      float4 p0 = spts[j0], p1 = spts[j1];
      float q0 = s2s[j0], q1 = s2s[j1];
      float d0A = fmaf(cAx, p0.x, fmaf(cAy, p0.y, fmaf(cAz, p0.z, fmaf(cAw, p0.w, q0 + s2A))));
      float d1A = fmaf(cAx, p1.x, fmaf(cAy, p1.y, fmaf(cAz, p1.z, fmaf(cAw, p1.w, q1 + s2A))));
      float d0B = fmaf(cBx, p0.x, fmaf(cBy, p0.y, fmaf(cBz, p0.z, fmaf(cBw, p0.w, q0 + s2B))));
      float d1B = fmaf(cBx, p1.x, fmaf(cBy, p1.y, fmaf(cBz, p1.z, fmaf(cBw, p1.w, q1 + s2B))));
      dbA[cc * 8 + ii] = (__float_as_uint(fmaxf(d0A, 0.f)) >> 16)
                       | (__float_as_uint(fmaxf(d1A, 0.f)) & 0xFFFF0000u);
      dbB[cc * 8 + ii] = (__float_as_uint(fmaxf(d0B, 0.f)) >> 16)
                       | (__float_as_uint(fmaxf(d1B, 0.f)) & 0xFFFF0000u);
    }
  }

  unsigned hA = bisect_seed(dbA);
  unsigned hB = bisect_seed(dbB);
  float t0A = __uint_as_float((hA << 16) | 0xFFFFu);
  float t0B = __uint_as_float((hB << 16) | 0xFFFFu);

  // ---- main scan: all 16 chunks, filtered ballot-prefix append ----
  int cntA = 0, cntB = 0;
  for (int c = 0; c < 16; ++c) {
    __syncthreads();
    for (int t = tid; t < 1024; t += 512) {
      float4 p = s4[c * 1024 + t];
      spts[t] = p;
      s2s[t] = fmaf(p.x, p.x, fmaf(p.y, p.y, fmaf(p.z, p.z, p.w * p.w)));
    }
    __syncthreads();
    #pragma unroll 4
    for (int i = 0; i < 16; ++i) {
      int j = i * 64 + lane;
      float4 p = spts[j];
      float q = s2s[j];
      float dA = fmaf(cAx, p.x, fmaf(cAy, p.y, fmaf(cAz, p.z, fmaf(cAw, p.w, q + s2A))));
      float dB = fmaf(cBx, p.x, fmaf(cBy, p.y, fmaf(cBz, p.z, fmaf(cBw, p.w, q + s2B))));
      unsigned gi = (unsigned)((c << 10) + (i << 6) + lane);
      bool kA = dA <= t0A;
      unsigned long long mA = __ballot(kA);
      if (mA) {
        int pos = cntA + (int)mbcnt64(mA);
        if (kA && pos < KNN_CAP)
          bufA[pos] = (__float_as_uint(fmaxf(dA, 0.f)) & 0xFFFFC000u) | gi;
        cntA += (int)__popcll(mA);
      }
      bool kB = dB <= t0B;
      unsigned long long mB = __ballot(kB);
      if (mB) {
        int pos = cntB + (int)mbcnt64(mB);
        if (kB && pos < KNN_CAP)
          bufB[pos] = (__float_as_uint(fmaxf(dB, 0.f)) & 0xFFFFC000u) | gi;
        cntB += (int)__popcll(mB);
      }
    }
    if (cntA > SOFT_CAP) {
      CompactRes r = compact_buf(bufA, cntA, lane);
      cntA = r.cnt; t0A = __uint_as_float(r.thr | 0x3FFFu);
    }
    if (cntB > SOFT_CAP) {
      CompactRes r = compact_buf(bufB, cntB, lane);
      cntB = r.cnt; t0B = __uint_as_float(r.thr | 0x3FFFu);
    }
  }

  if (cntA > 96) { CompactRes r = compact_buf(bufA, cntA, lane); cntA = r.cnt; }
  if (cntB > 96) { CompactRes r = compact_buf(bufB, cntB, lane); cntB = r.cnt; }

  // ---- finalists: exact d2 recompute + bitonic-128 sort + emit top-40 ----
  #pragma unroll
  for (int rr = 0; rr < 2; ++rr) {
    unsigned* bufR = rr ? bufB : bufA;
    int m = rr ? cntB : cntA;
    const float cx = rr ? cBx : cAx, cy = rr ? cBy : cAy;
    const float cz = rr ? cBz : cAz, cw = rr ? cBw : cAw;
    const float s2i = rr ? s2B : s2A;
    const int row = rr ? rB : rA;

    unsigned long long e0 = ~0ull, e1 = ~0ull;
    {
      int sl0 = lane * 2, sl1 = lane * 2 + 1;
      if (sl0 < m) {
        unsigned key = bufR[sl0];
        unsigned idx = key & 0x3FFFu;
        float4 p = s4[idx];
        float qj = fmaf(p.x, p.x, fmaf(p.y, p.y, fmaf(p.z, p.z, p.w * p.w)));
        float d = fmaf(cx, p.x, fmaf(cy, p.y, fmaf(cz, p.z, fmaf(cw, p.w, qj + s2i))));
        e0 = (((unsigned long long)__float_as_uint(fmaxf(d, 0.f))) << 32) | idx;
      }
      if (sl1 < m) {
        unsigned key = bufR[sl1];
        unsigned idx = key & 0x3FFFu;
        float4 p = s4[idx];
        float qj = fmaf(p.x, p.x, fmaf(p.y, p.y, fmaf(p.z, p.z, p.w * p.w)));
        float d = fmaf(cx, p.x, fmaf(cy, p.y, fmaf(cz, p.z, fmaf(cw, p.w, qj + s2i))));
        e1 = (((unsigned long long)__float_as_uint(fmaxf(d, 0.f))) << 32) | idx;
      }
    }

    #pragma unroll
    for (int k = 2; k <= 128; k <<= 1) {
      #pragma unroll
      for (int jj = k >> 1; jj >= 1; jj >>= 1) {
        bool up = (((lane * 2) & k) == 0);
        if (jj == 1) {
          unsigned long long a = (e0 < e1) ? e0 : e1;
          unsigned long long b = (e0 < e1) ? e1 : e0;
          e0 = up ? a : b; e1 = up ? b : a;
        } else {
          int lj = jj >> 1;
          bool lower = ((lane & lj) == 0);
          bool tm = (up == lower);
          unsigned long long o0 = __shfl_xor(e0, lj, 64);
          e0 = tm ? ((e0 < o0) ? e0 : o0) : ((e0 > o0) ? e0 : o0);
          unsigned long long o1 = __shfl_xor(e1, lj, 64);
          e1 = tm ? ((e1 < o1) ? e1 : o1) : ((e1 > o1) ? e1 : o1);
        }
      }
    }

    const int ob = row * KNN_K;
    if (lane < 20) {
      int v0 = lane * 2;
      idx_out[ob + v0] = (unsigned short)(e0 & 0xFFFFu);
      w_out[ob + v0] = f2bf(__expf(-10.f * __uint_as_float((unsigned)(e0 >> 32))));
      int v1 = v0 + 1;
      idx_out[ob + v1] = (unsigned short)(e1 & 0xFFFFu);
      w_out[ob + v1] = f2bf(__expf(-10.f * __uint_as_float((unsigned)(e1 >> 32))));
    }
  }
}

// ---------------------------------------------------------------------------
// Aggregation: Aout[i] = [mean_k h[idx]*w | max_k h[idx]*w]  (N x 128, bf16).
// ---------------------------------------------------------------------------
__global__ __launch_bounds__(256, 4) void agg_k(
    const unsigned short* __restrict__ h, const unsigned short* __restrict__ idxb,
    const unsigned short* __restrict__ wb, unsigned short* __restrict__ Aout)
{
  const int row = blockIdx.x * 4 + (threadIdx.x >> 6);
  const int lane = threadIdx.x & 63;
  const int base = row * KNN_K;
  float mean = 0.f, mx = -INFINITY;
  #pragma unroll 4
  for (int k = 0; k < KNN_K; ++k) {
    int j = idxb[base + k];
    float wv = bf2f(wb[base + k]);
    float m = bf2f(h[(size_t)j * 64 + lane]) * wv;
    mean += m;
    mx = fmaxf(mx, m);
  }
  Aout[(size_t)row * 128 + lane] = f2bf(mean * (1.f / 40.f));
  Aout[(size_t)row * 128 + 64 + lane] = f2bf(mx);
}

// ---------------------------------------------------------------------------
extern "C" void kernel_launch(void* const* d_in, const int* in_sizes, int n_in,
                              void* d_out, int out_size, void* d_ws, size_t ws_size,
                              hipStream_t stream)
{
  const float* x    = (const float*)d_in[0];
  const float* fc1W = (const float*)d_in[1];  const float* fc1b = (const float*)d_in[2];
  const float* fc2W = (const float*)d_in[3];  const float* fc2b = (const float*)d_in[4];
  const float* gsW  = (const float*)d_in[5];  const float* gsb  = (const float*)d_in[6];
  const float* ghW  = (const float*)d_in[7];  const float* ghb  = (const float*)d_in[8];
  const float* goW  = (const float*)d_in[9];  const float* gob  = (const float*)d_in[10];
  const float* d1W  = (const float*)d_in[11]; const float* d1b  = (const float*)d_in[12];
  const float* d2W  = (const float*)d_in[13]; const float* d2b  = (const float*)d_in[14];
  const float* d3W  = (const float*)d_in[15]; const float* d3b  = (const float*)d_in[16];
  const float* fc3W = (const float*)d_in[17]; const float* fc3b = (const float*)d_in[18];
  const float* fc4W = (const float*)d_in[19]; const float* fc4b = (const float*)d_in[20];
  float* out = (float*)d_out;

  // ---- workspace layout: ~14.5 MiB (bf16 activations, u16 idx) ----
  const size_t N = NPTS;
  u16* X    = (u16*)d_ws;
  u16* Abuf = X + N * 128;
  u16* T    = Abuf + N * 128;
  u16* IDX  = T + N * 128;
  u16* WNB  = IDX + N * 40;
  float* S = (float*)Abuf;        // N*4 fp32 aliased at start of Abuf
  u16* H = T;                     // N*64 bf16 aliased at start of T

  gemm_k<128, true, float, u16><<<NPTS / 64, 256, 0, stream>>>(
      x, 9, x, 9, 9, fc1W, fc1b, T, 128, 9);
  gemm_mfma_k<128, true><<<NPTS / 64, 256, 0, stream>>>(
      T, 128, T, 128, 128, fc2W, fc2b, X, 128, 128);

  for (int l = 0; l < 4; ++l) {
    gemm4_k<false, float><<<NPTS / 256, 256, 0, stream>>>(
        X, 128, gsW + l * 128 * 4, gsb + l * 4, S, 128);
    gemm_mfma_k<64, false><<<NPTS / 64, 256, 0, stream>>>(
        X, 128, X, 128, 128, ghW + l * 128 * 64, ghb + l * 64, H, 64, 128);
    knn_k<<<NPTS / 16, 512, 0, stream>>>(S, IDX, WNB);
    agg_k<<<NPTS / 4, 256, 0, stream>>>(H, IDX, WNB, Abuf);
    gemm_mfma_k<128, false><<<NPTS / 64, 256, 0, stream>>>(
        X, 128, Abuf, 128, 128, goW + l * 256 * 128, gob + l * 128, T, 128, 256);
    gemm_mfma_k<128, true><<<NPTS / 64, 256, 0, stream>>>(
        T, 128, T, 128, 128, d1W + l * 128 * 128, d1b + l * 128, Abuf, 128, 128);
    gemm_mfma_k<128, true><<<NPTS / 64, 256, 0, stream>>>(
        Abuf, 128, Abuf, 128, 128, d2W + l * 128 * 128, d2b + l * 128, T, 128, 128);
    gemm_mfma_k<128, true><<<NPTS / 64, 256, 0, stream>>>(
        T, 128, T, 128, 128, d3W + l * 128 * 128, d3b + l * 128, X, 128, 128);
  }

  gemm_mfma_k<128, true><<<NPTS / 64, 256, 0, stream>>>(
      X, 128, X, 128, 128, fc3W, fc3b, T, 128, 128);
  gemm4_k<false, float><<<NPTS / 256, 256, 0, stream>>>(
      T, 128, fc4W, fc4b, out, 128);
}

// Round 5
// 4175.546 us; speedup vs baseline: 1.0355x; 1.0020x over previous
//
#include <hip/hip_runtime.h>
#include <math.h>

// Problem constants (from reference)
#define NPTS     16384
#define KNN_K    40
#define KNN_CAP  448   // per-row survivor buffer (u32 keys); soft-compact keeps it safe
#define SOFT_CAP 320   // compact when count exceeds this at a chunk boundary

typedef unsigned short u16;
typedef __attribute__((ext_vector_type(8))) short bf16x8;
typedef __attribute__((ext_vector_type(4))) float f32x4;

// ---- bf16 (stored as ushort bits) helpers: fp32 compute, bf16 storage -----
static __device__ __forceinline__ float bf2f(unsigned short h) {
  return __uint_as_float(((unsigned)h) << 16);
}
static __device__ __forceinline__ unsigned short f2bf(float f) {
  unsigned u = __float_as_uint(f);
  unsigned r = (u + 0x7fffu + ((u >> 16) & 1u)) >> 16;   // round-nearest-even
  return (unsigned short)r;
}
static __device__ __forceinline__ float ldf(const float* p) { return *p; }
static __device__ __forceinline__ float ldf(const unsigned short* p) { return bf2f(*p); }

static __device__ __forceinline__ float rfl(float x) {   // readfirstlane -> SGPR
  return __uint_as_float(__builtin_amdgcn_readfirstlane(__float_as_uint(x)));
}
static __device__ __forceinline__ unsigned mbcnt64(unsigned long long m) {
  return __builtin_amdgcn_mbcnt_hi((unsigned)(m >> 32),
                                   __builtin_amdgcn_mbcnt_lo((unsigned)m, 0u));
}

// ---------------------------------------------------------------------------
// MFMA GEMM: C[N x MCOLS] = (relu?)(concat(A1,A2) @ W + bias), bf16 in/out,
// fp32 weights split hi/lo bf16 (W = Whi + Wlo) -> two chained MFMAs keep
// effective weight precision ~2^-18 (accuracy stays activation-bf16-bound).
// 64-row x MCOLS tile per block, 256 thr = 4 waves; K staged in 32-chunks.
// ---------------------------------------------------------------------------
template<int MCOLS, bool RELU>
__global__ __launch_bounds__(256, 2) void gemm_mfma_k(
    const u16* __restrict__ A1, int lda1,
    const u16* __restrict__ A2, int lda2, int K1,
    const float* __restrict__ W, const float* __restrict__ bias,
    u16* __restrict__ C, int ldc, int K)
{
  constexpr int CT = MCOLS / 64;      // 16-col tiles per wave (128->2, 64->1)
  constexpr int AST = 40;             // LDS row stride (32 k + 8 pad), 16B-aligned
  __shared__ u16 lds[64 * AST + 2 * MCOLS * AST];
  u16* As = lds;
  u16* Wh = lds + 64 * AST;
  u16* Wl = Wh + MCOLS * AST;

  const int tid = threadIdx.x;
  const int lane = tid & 63;
  const int w = tid >> 6;
  const int row0 = blockIdx.x * 64;

  f32x4 acc[4][CT];
  #pragma unroll
  for (int rt = 0; rt < 4; ++rt)
    #pragma unroll
    for (int ct = 0; ct < CT; ++ct)
      acc[rt][ct] = (f32x4){0.f, 0.f, 0.f, 0.f};

  const int rbase = lane & 15;
  const int koff = (lane >> 4) * 8;

  for (int k0 = 0; k0 < K; k0 += 32) {
    __syncthreads();
    // stage A tile 64 x 32 (16B per thread; concat source never straddles K1)
    {
      int r = tid >> 2, seg = tid & 3;
      int kk = k0 + seg * 8;
      const u16* src = (kk < K1) ? &A1[(size_t)(row0 + r) * lda1 + kk]
                                 : &A2[(size_t)(row0 + r) * lda2 + (kk - K1)];
      *(uint4*)&As[r * AST + seg * 8] = *(const uint4*)src;
    }
    // stage W chunk 32 x MCOLS, transposed + hi/lo split
    for (int l = tid; l < 32 * MCOLS; l += 256) {
      int n = l & (MCOLS - 1), kk = l / MCOLS;
      float wv = W[(size_t)(k0 + kk) * MCOLS + n];
      u16 h = f2bf(wv);
      Wh[n * AST + kk] = h;
      Wl[n * AST + kk] = f2bf(wv - bf2f(h));
    }
    __syncthreads();

    bf16x8 a[4];
    #pragma unroll
    for (int rt = 0; rt < 4; ++rt)
      a[rt] = *(const bf16x8*)&As[(rt * 16 + rbase) * AST + koff];
    #pragma unroll
    for (int ct = 0; ct < CT; ++ct) {
      int col = (w * CT + ct) * 16 + rbase;
      bf16x8 bh = *(const bf16x8*)&Wh[col * AST + koff];
      bf16x8 bl = *(const bf16x8*)&Wl[col * AST + koff];
      #pragma unroll
      for (int rt = 0; rt < 4; ++rt) {
        acc[rt][ct] = __builtin_amdgcn_mfma_f32_16x16x32_bf16(a[rt], bh, acc[rt][ct], 0, 0, 0);
        acc[rt][ct] = __builtin_amdgcn_mfma_f32_16x16x32_bf16(a[rt], bl, acc[rt][ct], 0, 0, 0);
      }
    }
  }

  // epilogue: bias + relu, bf16 pack via LDS for coalesced stores
  __syncthreads();
  constexpr int CST = MCOLS + 8;
  u16* Ct = lds;
  const int rq = (lane >> 4) * 4;
  #pragma unroll
  for (int ct = 0; ct < CT; ++ct) {
    int col = (w * CT + ct) * 16 + rbase;
    float bv = bias[col];
    #pragma unroll
    for (int rt = 0; rt < 4; ++rt) {
      #pragma unroll
      for (int q = 0; q < 4; ++q) {
        float v = acc[rt][ct][q] + bv;
        if (RELU) v = fmaxf(v, 0.f);
        Ct[(rt * 16 + rq + q) * CST + col] = f2bf(v);
      }
    }
  }
  __syncthreads();
  constexpr int SEGS = MCOLS / 8;
  for (int l = tid; l < 64 * SEGS; l += 256) {
    int r = l / SEGS, sg = l % SEGS;
    *(uint4*)&C[(size_t)(row0 + r) * ldc + sg * 8] = *(const uint4*)&Ct[r * CST + sg * 8];
  }
}

// ---------------------------------------------------------------------------
// VALU GEMM (fc1 only: K=9, fp32 input)
// ---------------------------------------------------------------------------
template<int MCOLS, bool RELU, typename TIN, typename TOUT>
__global__ __launch_bounds__(256, 4) void gemm_k(
    const TIN* __restrict__ A1, int lda1,
    const TIN* __restrict__ A2, int lda2, int K1,
    const float* __restrict__ W, const float* __restrict__ bias,
    TOUT* __restrict__ C, int ldc, int K)
{
  constexpr int TCS = MCOLS / 8;
  constexpr int RPT = (64 * TCS) / 256;
  __shared__ float Asl[64][33];
  __shared__ float Ws[32][MCOLS];
  const int tid = threadIdx.x;
  const int row0 = blockIdx.x * 64;
  const int tc = tid % TCS, tr = tid / TCS;

  float acc[RPT][8];
  #pragma unroll
  for (int p = 0; p < RPT; ++p)
    #pragma unroll
    for (int q = 0; q < 8; ++q) acc[p][q] = 0.f;

  for (int k0 = 0; k0 < K; k0 += 32) {
    __syncthreads();
    for (int l = tid; l < 64 * 32; l += 256) {
      int r = l >> 5, c = l & 31, k = k0 + c;
      float v = 0.f;
      if (k < K) v = (k < K1) ? ldf(&A1[(size_t)(row0 + r) * lda1 + k])
                              : ldf(&A2[(size_t)(row0 + r) * lda2 + (k - K1)]);
      Asl[r][c] = v;
    }
    for (int l = tid; l < 32 * MCOLS; l += 256) {
      int kr = l / MCOLS, c = l % MCOLS, k = k0 + kr;
      Ws[kr][c] = (k < K) ? W[(size_t)k * MCOLS + c] : 0.f;
    }
    __syncthreads();
    #pragma unroll
    for (int kk = 0; kk < 32; ++kk) {
      float a[RPT];
      #pragma unroll
      for (int p = 0; p < RPT; ++p) a[p] = Asl[tr * RPT + p][kk];
      const float4 w0 = *(const float4*)&Ws[kk][tc * 8];
      const float4 w1 = *(const float4*)&Ws[kk][tc * 8 + 4];
      #pragma unroll
      for (int p = 0; p < RPT; ++p) {
        acc[p][0] = fmaf(a[p], w0.x, acc[p][0]);
        acc[p][1] = fmaf(a[p], w0.y, acc[p][1]);
        acc[p][2] = fmaf(a[p], w0.z, acc[p][2]);
        acc[p][3] = fmaf(a[p], w0.w, acc[p][3]);
        acc[p][4] = fmaf(a[p], w1.x, acc[p][4]);
        acc[p][5] = fmaf(a[p], w1.y, acc[p][5]);
        acc[p][6] = fmaf(a[p], w1.z, acc[p][6]);
        acc[p][7] = fmaf(a[p], w1.w, acc[p][7]);
      }
    }
  }

  const float4 b0 = *(const float4*)&bias[tc * 8];
  const float4 b1 = *(const float4*)&bias[tc * 8 + 4];
  #pragma unroll
  for (int p = 0; p < RPT; ++p) {
    int r = row0 + tr * RPT + p;
    float o[8];
    o[0] = acc[p][0] + b0.x; o[1] = acc[p][1] + b0.y;
    o[2] = acc[p][2] + b0.z; o[3] = acc[p][3] + b0.w;
    o[4] = acc[p][4] + b1.x; o[5] = acc[p][5] + b1.y;
    o[6] = acc[p][6] + b1.z; o[7] = acc[p][7] + b1.w;
    if (RELU) {
      #pragma unroll
      for (int q = 0; q < 8; ++q) o[q] = fmaxf(o[q], 0.f);
    }
    if constexpr (sizeof(TOUT) == 2) {
      unsigned p0 = (unsigned)f2bf(o[0]) | ((unsigned)f2bf(o[1]) << 16);
      unsigned p1 = (unsigned)f2bf(o[2]) | ((unsigned)f2bf(o[3]) << 16);
      unsigned p2 = (unsigned)f2bf(o[4]) | ((unsigned)f2bf(o[5]) << 16);
      unsigned p3 = (unsigned)f2bf(o[6]) | ((unsigned)f2bf(o[7]) << 16);
      uint4 pk = make_uint4(p0, p1, p2, p3);
      *(uint4*)&C[(size_t)r * ldc + tc * 8] = pk;
    } else {
      float4 o0, o1;
      o0.x = o[0]; o0.y = o[1]; o0.z = o[2]; o0.w = o[3];
      o1.x = o[4]; o1.y = o[5]; o1.z = o[6]; o1.w = o[7];
      *(float4*)&C[(size_t)r * ldc + tc * 8] = o0;
      *(float4*)&C[(size_t)r * ldc + tc * 8 + 4] = o1;
    }
  }
}

// ---------------------------------------------------------------------------
// Small-M GEMM (M = 4): lin_s and fc4. One thread per row, bf16 input.
// ---------------------------------------------------------------------------
template<bool RELU, typename TOUT>
__global__ __launch_bounds__(256, 4) void gemm4_k(
    const u16* __restrict__ A, int lda,
    const float* __restrict__ W, const float* __restrict__ bias,
    TOUT* __restrict__ C, int K)
{
  __shared__ float Wsl[128 * 4];
  __shared__ float bl[4];
  const int tid = threadIdx.x;
  for (int l = tid; l < K * 4; l += 256) Wsl[l] = W[l];
  if (tid < 4) bl[tid] = bias[tid];
  __syncthreads();
  const int row = blockIdx.x * 256 + tid;
  const u16* ap = A + (size_t)row * lda;
  float a0 = bl[0], a1 = bl[1], a2 = bl[2], a3 = bl[3];
  for (int k8 = 0; k8 < K; k8 += 8) {
    uint4 pk = *(const uint4*)&ap[k8];
    unsigned uu[4] = {pk.x, pk.y, pk.z, pk.w};
    #pragma unroll
    for (int q = 0; q < 4; ++q) {
      float flo = __uint_as_float(uu[q] << 16);
      float fhi = __uint_as_float(uu[q] & 0xFFFF0000u);
      const float* wr0 = &Wsl[(k8 + 2 * q) * 4];
      a0 = fmaf(flo, wr0[0], a0); a1 = fmaf(flo, wr0[1], a1);
      a2 = fmaf(flo, wr0[2], a2); a3 = fmaf(flo, wr0[3], a3);
      a0 = fmaf(fhi, wr0[4], a0); a1 = fmaf(fhi, wr0[5], a1);
      a2 = fmaf(fhi, wr0[6], a2); a3 = fmaf(fhi, wr0[7], a3);
    }
  }
  if (RELU) {
    a0 = fmaxf(a0, 0.f); a1 = fmaxf(a1, 0.f);
    a2 = fmaxf(a2, 0.f); a3 = fmaxf(a3, 0.f);
  }
  if constexpr (sizeof(TOUT) == 2) {
    C[(size_t)row * 4 + 0] = (TOUT)f2bf(a0);
    C[(size_t)row * 4 + 1] = (TOUT)f2bf(a1);
    C[(size_t)row * 4 + 2] = (TOUT)f2bf(a2);
    C[(size_t)row * 4 + 3] = (TOUT)f2bf(a3);
  } else {
    float4 o; o.x = a0; o.y = a1; o.z = a2; o.w = a3;
    *(float4*)&C[(size_t)row * 4] = o;
  }
}

// ---------------------------------------------------------------------------
// kNN v2 (inline-fixed): 2 rows/wave, 16 rows per 512-thread block. u32 keys
// (trunc18(d2) | idx14). The helpers MUST be __forceinline__: out-of-line
// calls forced the register seed arrays into scratch (43 MB of spill traffic
// per dispatch in rounds 3-4).
// ---------------------------------------------------------------------------
struct CompactRes { int cnt; unsigned thr; };

static __device__ __forceinline__ CompactRes compact_buf(unsigned* bufR, int cnt, int lane) {
  int n = min(cnt, KNN_CAP);
  int lo = -1, hi = 0x7FFFFFFF, chi = n;
  for (int it = 0; it < 32; ++it) {
    if (chi <= 96) break;
    int mid = lo + ((hi - lo) >> 1);
    int lc = 0;
    for (int base = 0; base < n; base += 64) {
      int i = base + lane;
      bool c = (i < n) && (bufR[i] <= (unsigned)mid);
      lc += (int)__popcll(__ballot(c));
    }
    if (lc >= 40) { hi = mid; chi = lc; } else lo = mid;
  }
  unsigned thr = (unsigned)hi;
  int out = 0;
  for (int base = 0; base < n; base += 64) {
    int i = base + lane;
    unsigned key = (i < n) ? bufR[i] : 0xFFFFFFFFu;
    bool keep = (i < n) && (key <= thr);
    unsigned long long mk = __ballot(keep);
    unsigned pre = mbcnt64(mk);
    if (keep) bufR[out + (int)pre] = key;   // front-compaction: write idx <= read idx
    out += (int)__popcll(mk);
  }
  CompactRes r; r.cnt = out; r.thr = thr;
  return r;
}

static __device__ __forceinline__ unsigned bisect_seed(const unsigned (&db)[16]) {
  int lo = -1, hi = 0x7F7F, chi = 2048;
  for (int it = 0; it < 20; ++it) {
    if (chi <= 41 || (hi - lo) <= 1) break;
    int mid = lo + ((hi - lo) >> 1);
    unsigned mhi = ((unsigned)mid << 16) | 0xFFFFu;
    int lc = 0;
    #pragma unroll
    for (int i = 0; i < 16; ++i) {
      lc += (int)__popcll(__ballot((db[i] & 0xFFFFu) <= (unsigned)mid));
      lc += (int)__popcll(__ballot(db[i] <= mhi));
    }
    if (lc >= 40) { hi = mid; chi = lc; } else lo = mid;
  }
  return (unsigned)hi;
}

__global__ __launch_bounds__(512, 4) void knn_k(
    const float* __restrict__ s,
    unsigned short* __restrict__ idx_out, unsigned short* __restrict__ w_out)
{
  __shared__ float4 spts[1024];
  __shared__ float  s2s[1024];
  __shared__ unsigned buf[16][KNN_CAP];

  const int tid = threadIdx.x;
  const int lane = tid & 63;
  const int w = tid >> 6;
  const int rA = blockIdx.x * 16 + w * 2;
  const int rB = rA + 1;
  const float4* s4 = (const float4*)s;

  float4 sa = s4[rA], sb = s4[rB];
  const float cAx = rfl(-2.f * sa.x), cAy = rfl(-2.f * sa.y);
  const float cAz = rfl(-2.f * sa.z), cAw = rfl(-2.f * sa.w);
  const float s2A = rfl(fmaf(sa.x, sa.x, fmaf(sa.y, sa.y, fmaf(sa.z, sa.z, sa.w * sa.w))));
  const float cBx = rfl(-2.f * sb.x), cBy = rfl(-2.f * sb.y);
  const float cBz = rfl(-2.f * sb.z), cBw = rfl(-2.f * sb.w);
  const float s2B = rfl(fmaf(sb.x, sb.x, fmaf(sb.y, sb.y, fmaf(sb.z, sb.z, sb.w * sb.w))));

  unsigned* bufA = buf[2 * w];
  unsigned* bufB = buf[2 * w + 1];

  // ---- seed: chunks 0,1 -> u16-packed d2 in registers (16/row) ----
  unsigned dbA[16], dbB[16];
  #pragma unroll
  for (int cc = 0; cc < 2; ++cc) {
    __syncthreads();
    for (int t = tid; t < 1024; t += 512) {
      float4 p = s4[cc * 1024 + t];
      spts[t] = p;
      s2s[t] = fmaf(p.x, p.x, fmaf(p.y, p.y, fmaf(p.z, p.z, p.w * p.w)));
    }
    __syncthreads();
    #pragma unroll
    for (int ii = 0; ii < 8; ++ii) {
      int j0 = (2 * ii) * 64 + lane, j1 = (2 * ii + 1) * 64 + lane;
      float4 p0 = spts[j0], p1 = spts[j1];
      float q0 = s2s[j0], q1 = s2s[j1];
      float d0A = fmaf(cAx, p0.x, fmaf(cAy, p0.y, fmaf(cAz, p0.z, fmaf(cAw, p0.w, q0 + s2A))));
      float d1A = fmaf(cAx, p1.x, fmaf(cAy, p1.y, fmaf(cAz, p1.z, fmaf(cAw, p1.w, q1 + s2A))));
      float d0B = fmaf(cBx, p0.x, fmaf(cBy, p0.y, fmaf(cBz, p0.z, fmaf(cBw, p0.w, q0 + s2B))));
      float d1B = fmaf(cBx, p1.x, fmaf(cBy, p1.y, fmaf(cBz, p1.z, fmaf(cBw, p1.w, q1 + s2B))));
      dbA[cc * 8 + ii] = (__float_as_uint(fmaxf(d0A, 0.f)) >> 16)
                       | (__float_as_uint(fmaxf(d1A, 0.f)) & 0xFFFF0000u);
      dbB[cc * 8 + ii] = (__float_as_uint(fmaxf(d0B, 0.f)) >> 16)
                       | (__float_as_uint(fmaxf(d1B, 0.f)) & 0xFFFF0000u);
    }
  }

  unsigned hA = bisect_seed(dbA);
  unsigned hB = bisect_seed(dbB);
  float t0A = __uint_as_float((hA << 16) | 0xFFFFu);
  float t0B = __uint_as_float((hB << 16) | 0xFFFFu);

  // ---- main scan: all 16 chunks, filtered ballot-prefix append ----
  int cntA = 0, cntB = 0;
  for (int c = 0; c < 16; ++c) {
    __syncthreads();
    for (int t = tid; t < 1024; t += 512) {
      float4 p = s4[c * 1024 + t];
      spts[t] = p;
      s2s[t] = fmaf(p.x, p.x, fmaf(p.y, p.y, fmaf(p.z, p.z, p.w * p.w)));
    }
    __syncthreads();
    #pragma unroll 4
    for (int i = 0; i < 16; ++i) {
      int j = i * 64 + lane;
      float4 p = spts[j];
      float q = s2s[j];
      float dA = fmaf(cAx, p.x, fmaf(cAy, p.y, fmaf(cAz, p.z, fmaf(cAw, p.w, q + s2A))));
      float dB = fmaf(cBx, p.x, fmaf(cBy, p.y, fmaf(cBz, p.z, fmaf(cBw, p.w, q + s2B))));
      unsigned gi = (unsigned)((c << 10) + (i << 6) + lane);
      bool kA = dA <= t0A;
      unsigned long long mA = __ballot(kA);
      if (mA) {
        int pos = cntA + (int)mbcnt64(mA);
        if (kA && pos < KNN_CAP)
          bufA[pos] = (__float_as_uint(fmaxf(dA, 0.f)) & 0xFFFFC000u) | gi;
        cntA += (int)__popcll(mA);
      }
      bool kB = dB <= t0B;
      unsigned long long mB = __ballot(kB);
      if (mB) {
        int pos = cntB + (int)mbcnt64(mB);
        if (kB && pos < KNN_CAP)
          bufB[pos] = (__float_as_uint(fmaxf(dB, 0.f)) & 0xFFFFC000u) | gi;
        cntB += (int)__popcll(mB);
      }
    }
    if (cntA > SOFT_CAP) {
      CompactRes r = compact_buf(bufA, cntA, lane);
      cntA = r.cnt; t0A = __uint_as_float(r.thr | 0x3FFFu);
    }
    if (cntB > SOFT_CAP) {
      CompactRes r = compact_buf(bufB, cntB, lane);
      cntB = r.cnt; t0B = __uint_as_float(r.thr | 0x3FFFu);
    }
  }

  if (cntA > 96) { CompactRes r = compact_buf(bufA, cntA, lane); cntA = r.cnt; }
  if (cntB > 96) { CompactRes r = compact_buf(bufB, cntB, lane); cntB = r.cnt; }

  // ---- finalists: exact d2 recompute + bitonic-128 sort + emit top-40 ----
  #pragma unroll
  for (int rr = 0; rr < 2; ++rr) {
    unsigned* bufR = rr ? bufB : bufA;
    int m = rr ? cntB : cntA;
    const float cx = rr ? cBx : cAx, cy = rr ? cBy : cAy;
    const float cz = rr ? cBz : cAz, cw = rr ? cBw : cAw;
    const float s2i = rr ? s2B : s2A;
    const int row = rr ? rB : rA;

    unsigned long long e0 = ~0ull, e1 = ~0ull;
    {
      int sl0 = lane * 2, sl1 = lane * 2 + 1;
      if (sl0 < m) {
        unsigned key = bufR[sl0];
        unsigned idx = key & 0x3FFFu;
        float4 p = s4[idx];
        float qj = fmaf(p.x, p.x, fmaf(p.y, p.y, fmaf(p.z, p.z, p.w * p.w)));
        float d = fmaf(cx, p.x, fmaf(cy, p.y, fmaf(cz, p.z, fmaf(cw, p.w, qj + s2i))));
        e0 = (((unsigned long long)__float_as_uint(fmaxf(d, 0.f))) << 32) | idx;
      }
      if (sl1 < m) {
        unsigned key = bufR[sl1];
        unsigned idx = key & 0x3FFFu;
        float4 p = s4[idx];
        float qj = fmaf(p.x, p.x, fmaf(p.y, p.y, fmaf(p.z, p.z, p.w * p.w)));
        float d = fmaf(cx, p.x, fmaf(cy, p.y, fmaf(cz, p.z, fmaf(cw, p.w, qj + s2i))));
        e1 = (((unsigned long long)__float_as_uint(fmaxf(d, 0.f))) << 32) | idx;
      }
    }

    #pragma unroll
    for (int k = 2; k <= 128; k <<= 1) {
      #pragma unroll
      for (int jj = k >> 1; jj >= 1; jj >>= 1) {
        bool up = (((lane * 2) & k) == 0);
        if (jj == 1) {
          unsigned long long a = (e0 < e1) ? e0 : e1;
          unsigned long long b = (e0 < e1) ? e1 : e0;
          e0 = up ? a : b; e1 = up ? b : a;
        } else {
          int lj = jj >> 1;
          bool lower = ((lane & lj) == 0);
          bool tm = (up == lower);
          unsigned long long o0 = __shfl_xor(e0, lj, 64);
          e0 = tm ? ((e0 < o0) ? e0 : o0) : ((e0 > o0) ? e0 : o0);
          unsigned long long o1 = __shfl_xor(e1, lj, 64);
          e1 = tm ? ((e1 < o1) ? e1 : o1) : ((e1 > o1) ? e1 : o1);
        }
      }
    }

    const int ob = row * KNN_K;
    if (lane < 20) {
      int v0 = lane * 2;
      idx_out[ob + v0] = (unsigned short)(e0 & 0xFFFFu);
      w_out[ob + v0] = f2bf(__expf(-10.f * __uint_as_float((unsigned)(e0 >> 32))));
      int v1 = v0 + 1;
      idx_out[ob + v1] = (unsigned short)(e1 & 0xFFFFu);
      w_out[ob + v1] = f2bf(__expf(-10.f * __uint_as_float((unsigned)(e1 >> 32))));
    }
  }
}

// ---------------------------------------------------------------------------
// Aggregation: Aout[i] = [mean_k h[idx]*w | max_k h[idx]*w]  (N x 128, bf16).
// ---------------------------------------------------------------------------
__global__ __launch_bounds__(256, 4) void agg_k(
    const unsigned short* __restrict__ h, const unsigned short* __restrict__ idxb,
    const unsigned short* __restrict__ wb, unsigned short* __restrict__ Aout)
{
  const int row = blockIdx.x * 4 + (threadIdx.x >> 6);
  const int lane = threadIdx.x & 63;
  const int base = row * KNN_K;
  float mean = 0.f, mx = -INFINITY;
  #pragma unroll 4
  for (int k = 0; k < KNN_K; ++k) {
    int j = idxb[base + k];
    float wv = bf2f(wb[base + k]);
    float m = bf2f(h[(size_t)j * 64 + lane]) * wv;
    mean += m;
    mx = fmaxf(mx, m);
  }
  Aout[(size_t)row * 128 + lane] = f2bf(mean * (1.f / 40.f));
  Aout[(size_t)row * 128 + 64 + lane] = f2bf(mx);
}

// ---------------------------------------------------------------------------
extern "C" void kernel_launch(void* const* d_in, const int* in_sizes, int n_in,
                              void* d_out, int out_size, void* d_ws, size_t ws_size,
                              hipStream_t stream)
{
  const float* x    = (const float*)d_in[0];
  const float* fc1W = (const float*)d_in[1];  const float* fc1b = (const float*)d_in[2];
  const float* fc2W = (const float*)d_in[3];  const float* fc2b = (const float*)d_in[4];
  const float* gsW  = (const float*)d_in[5];  const float* gsb  = (const float*)d_in[6];
  const float* ghW  = (const float*)d_in[7];  const float* ghb  = (const float*)d_in[8];
  const float* goW  = (const float*)d_in[9];  const float* gob  = (const float*)d_in[10];
  const float* d1W  = (const float*)d_in[11]; const float* d1b  = (const float*)d_in[12];
  const float* d2W  = (const float*)d_in[13]; const float* d2b  = (const float*)d_in[14];
  const float* d3W  = (const float*)d_in[15]; const float* d3b  = (const float*)d_in[16];
  const float* fc3W = (const float*)d_in[17]; const float* fc3b = (const float*)d_in[18];
  const float* fc4W = (const float*)d_in[19]; const float* fc4b = (const float*)d_in[20];
  float* out = (float*)d_out;

  // ---- workspace layout: ~14.5 MiB (bf16 activations, u16 idx) ----
  const size_t N = NPTS;
  u16* X    = (u16*)d_ws;
  u16* Abuf = X + N * 128;
  u16* T    = Abuf + N * 128;
  u16* IDX  = T + N * 128;
  u16* WNB  = IDX + N * 40;
  float* S = (float*)Abuf;        // N*4 fp32 aliased at start of Abuf
  u16* H = T;                     // N*64 bf16 aliased at start of T

  gemm_k<128, true, float, u16><<<NPTS / 64, 256, 0, stream>>>(
      x, 9, x, 9, 9, fc1W, fc1b, T, 128, 9);
  gemm_mfma_k<128, true><<<NPTS / 64, 256, 0, stream>>>(
      T, 128, T, 128, 128, fc2W, fc2b, X, 128, 128);

  for (int l = 0; l < 4; ++l) {
    gemm4_k<false, float><<<NPTS / 256, 256, 0, stream>>>(
        X, 128, gsW + l * 128 * 4, gsb + l * 4, S, 128);
    gemm_mfma_k<64, false><<<NPTS / 64, 256, 0, stream>>>(
        X, 128, X, 128, 128, ghW + l * 128 * 64, ghb + l * 64, H, 64, 128);
    knn_k<<<NPTS / 16, 512, 0, stream>>>(S, IDX, WNB);
    agg_k<<<NPTS / 4, 256, 0, stream>>>(H, IDX, WNB, Abuf);
    gemm_mfma_k<128, false><<<NPTS / 64, 256, 0, stream>>>(
        X, 128, Abuf, 128, 128, goW + l * 256 * 128, gob + l * 128, T, 128, 256);
    gemm_mfma_k<128, true><<<NPTS / 64, 256, 0, stream>>>(
        T, 128, T, 128, 128, d1W + l * 128 * 128, d1b + l * 128, Abuf, 128, 128);
    gemm_mfma_k<128, true><<<NPTS / 64, 256, 0, stream>>>(
        Abuf, 128, Abuf, 128, 128, d2W + l * 128 * 128, d2b + l * 128, T, 128, 128);
    gemm_mfma_k<128, true><<<NPTS / 64, 256, 0, stream>>>(
        T, 128, T, 128, 128, d3W + l * 128 * 128, d3b + l * 128, X, 128, 128);
  }

  gemm_mfma_k<128, true><<<NPTS / 64, 256, 0, stream>>>(
      X, 128, X, 128, 128, fc3W, fc3b, T, 128, 128);
  gemm4_k<false, float><<<NPTS / 256, 256, 0, stream>>>(
      T, 128, fc4W, fc4b, out, 128);
}

// Round 6
// 1531.856 us; speedup vs baseline: 2.8226x; 2.7258x over previous
//
#include <hip/hip_runtime.h>
#include <math.h>

// Problem constants (from reference)
#define NPTS     16384
#define KNN_K    40
#define KNN_CAP  448   // per-row survivor buffer (u32 keys)

typedef unsigned short u16;
typedef __attribute__((ext_vector_type(8))) short bf16x8;
typedef __attribute__((ext_vector_type(4))) float f32x4;

// ---- bf16 (stored as ushort bits) helpers: fp32 compute, bf16 storage -----
static __device__ __forceinline__ float bf2f(unsigned short h) {
  return __uint_as_float(((unsigned)h) << 16);
}
static __device__ __forceinline__ unsigned short f2bf(float f) {
  unsigned u = __float_as_uint(f);
  unsigned r = (u + 0x7fffu + ((u >> 16) & 1u)) >> 16;   // round-nearest-even
  return (unsigned short)r;
}
static __device__ __forceinline__ float ldf(const float* p) { return *p; }
static __device__ __forceinline__ float ldf(const unsigned short* p) { return bf2f(*p); }

static __device__ __forceinline__ float rfl(float x) {   // readfirstlane -> SGPR
  return __uint_as_float(__builtin_amdgcn_readfirstlane(__float_as_uint(x)));
}
static __device__ __forceinline__ unsigned mbcnt64(unsigned long long m) {
  return __builtin_amdgcn_mbcnt_hi((unsigned)(m >> 32),
                                   __builtin_amdgcn_mbcnt_lo((unsigned)m, 0u));
}

// ---------------------------------------------------------------------------
// MFMA GEMM: C[N x MCOLS] = (relu?)(concat(A1,A2) @ W + bias), bf16 in/out,
// fp32 weights split hi/lo bf16 (W = Whi + Wlo) -> two chained MFMAs keep
// effective weight precision ~2^-18 (accuracy stays activation-bf16-bound).
// ---------------------------------------------------------------------------
template<int MCOLS, bool RELU>
__global__ __launch_bounds__(256, 2) void gemm_mfma_k(
    const u16* __restrict__ A1, int lda1,
    const u16* __restrict__ A2, int lda2, int K1,
    const float* __restrict__ W, const float* __restrict__ bias,
    u16* __restrict__ C, int ldc, int K)
{
  constexpr int CT = MCOLS / 64;      // 16-col tiles per wave (128->2, 64->1)
  constexpr int AST = 40;             // LDS row stride (32 k + 8 pad), 16B-aligned
  __shared__ u16 lds[64 * AST + 2 * MCOLS * AST];
  u16* As = lds;
  u16* Wh = lds + 64 * AST;
  u16* Wl = Wh + MCOLS * AST;

  const int tid = threadIdx.x;
  const int lane = tid & 63;
  const int w = tid >> 6;
  const int row0 = blockIdx.x * 64;

  f32x4 acc[4][CT];
  #pragma unroll
  for (int rt = 0; rt < 4; ++rt)
    #pragma unroll
    for (int ct = 0; ct < CT; ++ct)
      acc[rt][ct] = (f32x4){0.f, 0.f, 0.f, 0.f};

  const int rbase = lane & 15;
  const int koff = (lane >> 4) * 8;

  for (int k0 = 0; k0 < K; k0 += 32) {
    __syncthreads();
    // stage A tile 64 x 32 (16B per thread; concat source never straddles K1)
    {
      int r = tid >> 2, seg = tid & 3;
      int kk = k0 + seg * 8;
      const u16* src = (kk < K1) ? &A1[(size_t)(row0 + r) * lda1 + kk]
                                 : &A2[(size_t)(row0 + r) * lda2 + (kk - K1)];
      *(uint4*)&As[r * AST + seg * 8] = *(const uint4*)src;
    }
    // stage W chunk 32 x MCOLS, transposed + hi/lo split
    for (int l = tid; l < 32 * MCOLS; l += 256) {
      int n = l & (MCOLS - 1), kk = l / MCOLS;
      float wv = W[(size_t)(k0 + kk) * MCOLS + n];
      u16 h = f2bf(wv);
      Wh[n * AST + kk] = h;
      Wl[n * AST + kk] = f2bf(wv - bf2f(h));
    }
    __syncthreads();

    bf16x8 a[4];
    #pragma unroll
    for (int rt = 0; rt < 4; ++rt)
      a[rt] = *(const bf16x8*)&As[(rt * 16 + rbase) * AST + koff];
    #pragma unroll
    for (int ct = 0; ct < CT; ++ct) {
      int col = (w * CT + ct) * 16 + rbase;
      bf16x8 bh = *(const bf16x8*)&Wh[col * AST + koff];
      bf16x8 bl = *(const bf16x8*)&Wl[col * AST + koff];
      #pragma unroll
      for (int rt = 0; rt < 4; ++rt) {
        acc[rt][ct] = __builtin_amdgcn_mfma_f32_16x16x32_bf16(a[rt], bh, acc[rt][ct], 0, 0, 0);
        acc[rt][ct] = __builtin_amdgcn_mfma_f32_16x16x32_bf16(a[rt], bl, acc[rt][ct], 0, 0, 0);
      }
    }
  }

  // epilogue: bias + relu, bf16 pack via LDS for coalesced stores
  __syncthreads();
  constexpr int CST = MCOLS + 8;
  u16* Ct = lds;
  const int rq = (lane >> 4) * 4;
  #pragma unroll
  for (int ct = 0; ct < CT; ++ct) {
    int col = (w * CT + ct) * 16 + rbase;
    float bv = bias[col];
    #pragma unroll
    for (int rt = 0; rt < 4; ++rt) {
      #pragma unroll
      for (int q = 0; q < 4; ++q) {
        float v = acc[rt][ct][q] + bv;
        if (RELU) v = fmaxf(v, 0.f);
        Ct[(rt * 16 + rq + q) * CST + col] = f2bf(v);
      }
    }
  }
  __syncthreads();
  constexpr int SEGS = MCOLS / 8;
  for (int l = tid; l < 64 * SEGS; l += 256) {
    int r = l / SEGS, sg = l % SEGS;
    *(uint4*)&C[(size_t)(row0 + r) * ldc + sg * 8] = *(const uint4*)&Ct[r * CST + sg * 8];
  }
}

// ---------------------------------------------------------------------------
// VALU GEMM (fc1 only: K=9, fp32 input)
// ---------------------------------------------------------------------------
template<int MCOLS, bool RELU, typename TIN, typename TOUT>
__global__ __launch_bounds__(256, 4) void gemm_k(
    const TIN* __restrict__ A1, int lda1,
    const TIN* __restrict__ A2, int lda2, int K1,
    const float* __restrict__ W, const float* __restrict__ bias,
    TOUT* __restrict__ C, int ldc, int K)
{
  constexpr int TCS = MCOLS / 8;
  constexpr int RPT = (64 * TCS) / 256;
  __shared__ float Asl[64][33];
  __shared__ float Ws[32][MCOLS];
  const int tid = threadIdx.x;
  const int row0 = blockIdx.x * 64;
  const int tc = tid % TCS, tr = tid / TCS;

  float acc[RPT][8];
  #pragma unroll
  for (int p = 0; p < RPT; ++p)
    #pragma unroll
    for (int q = 0; q < 8; ++q) acc[p][q] = 0.f;

  for (int k0 = 0; k0 < K; k0 += 32) {
    __syncthreads();
    for (int l = tid; l < 64 * 32; l += 256) {
      int r = l >> 5, c = l & 31, k = k0 + c;
      float v = 0.f;
      if (k < K) v = (k < K1) ? ldf(&A1[(size_t)(row0 + r) * lda1 + k])
                              : ldf(&A2[(size_t)(row0 + r) * lda2 + (k - K1)]);
      Asl[r][c] = v;
    }
    for (int l = tid; l < 32 * MCOLS; l += 256) {
      int kr = l / MCOLS, c = l % MCOLS, k = k0 + kr;
      Ws[kr][c] = (k < K) ? W[(size_t)k * MCOLS + c] : 0.f;
    }
    __syncthreads();
    #pragma unroll
    for (int kk = 0; kk < 32; ++kk) {
      float a[RPT];
      #pragma unroll
      for (int p = 0; p < RPT; ++p) a[p] = Asl[tr * RPT + p][kk];
      const float4 w0 = *(const float4*)&Ws[kk][tc * 8];
      const float4 w1 = *(const float4*)&Ws[kk][tc * 8 + 4];
      #pragma unroll
      for (int p = 0; p < RPT; ++p) {
        acc[p][0] = fmaf(a[p], w0.x, acc[p][0]);
        acc[p][1] = fmaf(a[p], w0.y, acc[p][1]);
        acc[p][2] = fmaf(a[p], w0.z, acc[p][2]);
        acc[p][3] = fmaf(a[p], w0.w, acc[p][3]);
        acc[p][4] = fmaf(a[p], w1.x, acc[p][4]);
        acc[p][5] = fmaf(a[p], w1.y, acc[p][5]);
        acc[p][6] = fmaf(a[p], w1.z, acc[p][6]);
        acc[p][7] = fmaf(a[p], w1.w, acc[p][7]);
      }
    }
  }

  const float4 b0 = *(const float4*)&bias[tc * 8];
  const float4 b1 = *(const float4*)&bias[tc * 8 + 4];
  #pragma unroll
  for (int p = 0; p < RPT; ++p) {
    int r = row0 + tr * RPT + p;
    float o[8];
    o[0] = acc[p][0] + b0.x; o[1] = acc[p][1] + b0.y;
    o[2] = acc[p][2] + b0.z; o[3] = acc[p][3] + b0.w;
    o[4] = acc[p][4] + b1.x; o[5] = acc[p][5] + b1.y;
    o[6] = acc[p][6] + b1.z; o[7] = acc[p][7] + b1.w;
    if (RELU) {
      #pragma unroll
      for (int q = 0; q < 8; ++q) o[q] = fmaxf(o[q], 0.f);
    }
    if constexpr (sizeof(TOUT) == 2) {
      unsigned p0 = (unsigned)f2bf(o[0]) | ((unsigned)f2bf(o[1]) << 16);
      unsigned p1 = (unsigned)f2bf(o[2]) | ((unsigned)f2bf(o[3]) << 16);
      unsigned p2 = (unsigned)f2bf(o[4]) | ((unsigned)f2bf(o[5]) << 16);
      unsigned p3 = (unsigned)f2bf(o[6]) | ((unsigned)f2bf(o[7]) << 16);
      uint4 pk = make_uint4(p0, p1, p2, p3);
      *(uint4*)&C[(size_t)r * ldc + tc * 8] = pk;
    } else {
      float4 o0, o1;
      o0.x = o[0]; o0.y = o[1]; o0.z = o[2]; o0.w = o[3];
      o1.x = o[4]; o1.y = o[5]; o1.z = o[6]; o1.w = o[7];
      *(float4*)&C[(size_t)r * ldc + tc * 8] = o0;
      *(float4*)&C[(size_t)r * ldc + tc * 8 + 4] = o1;
    }
  }
}

// ---------------------------------------------------------------------------
// Small-M GEMM (M = 4): lin_s and fc4. One thread per row, bf16 input.
// ---------------------------------------------------------------------------
template<bool RELU, typename TOUT>
__global__ __launch_bounds__(256, 4) void gemm4_k(
    const u16* __restrict__ A, int lda,
    const float* __restrict__ W, const float* __restrict__ bias,
    TOUT* __restrict__ C, int K)
{
  __shared__ float Wsl[128 * 4];
  __shared__ float bl[4];
  const int tid = threadIdx.x;
  for (int l = tid; l < K * 4; l += 256) Wsl[l] = W[l];
  if (tid < 4) bl[tid] = bias[tid];
  __syncthreads();
  const int row = blockIdx.x * 256 + tid;
  const u16* ap = A + (size_t)row * lda;
  float a0 = bl[0], a1 = bl[1], a2 = bl[2], a3 = bl[3];
  for (int k8 = 0; k8 < K; k8 += 8) {
    uint4 pk = *(const uint4*)&ap[k8];
    unsigned uu[4] = {pk.x, pk.y, pk.z, pk.w};
    #pragma unroll
    for (int q = 0; q < 4; ++q) {
      float flo = __uint_as_float(uu[q] << 16);
      float fhi = __uint_as_float(uu[q] & 0xFFFF0000u);
      const float* wr0 = &Wsl[(k8 + 2 * q) * 4];
      a0 = fmaf(flo, wr0[0], a0); a1 = fmaf(flo, wr0[1], a1);
      a2 = fmaf(flo, wr0[2], a2); a3 = fmaf(flo, wr0[3], a3);
      a0 = fmaf(fhi, wr0[4], a0); a1 = fmaf(fhi, wr0[5], a1);
      a2 = fmaf(fhi, wr0[6], a2); a3 = fmaf(fhi, wr0[7], a3);
    }
  }
  if (RELU) {
    a0 = fmaxf(a0, 0.f); a1 = fmaxf(a1, 0.f);
    a2 = fmaxf(a2, 0.f); a3 = fmaxf(a3, 0.f);
  }
  if constexpr (sizeof(TOUT) == 2) {
    C[(size_t)row * 4 + 0] = (TOUT)f2bf(a0);
    C[(size_t)row * 4 + 1] = (TOUT)f2bf(a1);
    C[(size_t)row * 4 + 2] = (TOUT)f2bf(a2);
    C[(size_t)row * 4 + 3] = (TOUT)f2bf(a3);
  } else {
    float4 o; o.x = a0; o.y = a1; o.z = a2; o.w = a3;
    *(float4*)&C[(size_t)row * 4] = o;
  }
}

// ---------------------------------------------------------------------------
// kNN v3: STREAMING top-k, no seed phase (rounds 3-5: the 32-reg seed arrays
// were spilled to scratch by the compiler's 64-VGPR occupancy heuristic ->
// 46 MB scratch traffic + scratch-capped occupancy). Start thr=+inf, append
// survivors; when buffer nears capacity, bisect-compact in LDS (threshold =
// current ~40..96th smallest key >= true 40th of full set, so no true
// neighbor is ever dropped). 2 rows/wave, 16 rows per 512-thr block.
// Keys: u32 (trunc18(d2) | idx14); exact d2 recomputed for <=128 finalists.
// ---------------------------------------------------------------------------
struct CompactRes { int cnt; unsigned thr; };

static __device__ __forceinline__ CompactRes compact_buf(unsigned* bufR, int cnt, int lane) {
  int n = min(cnt, KNN_CAP);
  int lo = -1, hi = 0x7FFFFFFF, chi = n;
  for (int it = 0; it < 32; ++it) {
    if (chi <= 96) break;
    int mid = lo + ((hi - lo) >> 1);
    int lc = 0;
    for (int base = 0; base < n; base += 64) {
      int i = base + lane;
      bool c = (i < n) && (bufR[i] <= (unsigned)mid);
      lc += (int)__popcll(__ballot(c));
    }
    if (lc >= 40) { hi = mid; chi = lc; } else lo = mid;
  }
  unsigned thr = (unsigned)hi;
  int out = 0;
  for (int base = 0; base < n; base += 64) {
    int i = base + lane;
    unsigned key = (i < n) ? bufR[i] : 0xFFFFFFFFu;
    bool keep = (i < n) && (key <= thr);
    unsigned long long mk = __ballot(keep);
    unsigned pre = mbcnt64(mk);
    if (keep) bufR[out + (int)pre] = key;   // front-compaction: write idx <= read idx
    out += (int)__popcll(mk);
  }
  CompactRes r; r.cnt = out; r.thr = thr;
  return r;
}

__global__ __launch_bounds__(512, 4) void knn_k(
    const float* __restrict__ s,
    unsigned short* __restrict__ idx_out, unsigned short* __restrict__ w_out)
{
  __shared__ float4 spts[1024];
  __shared__ float  s2s[1024];
  __shared__ unsigned buf[16][KNN_CAP];

  const int tid = threadIdx.x;
  const int lane = tid & 63;
  const int w = tid >> 6;
  const int rA = blockIdx.x * 16 + w * 2;
  const int rB = rA + 1;
  const float4* s4 = (const float4*)s;

  float4 sa = s4[rA], sb = s4[rB];
  const float cAx = rfl(-2.f * sa.x), cAy = rfl(-2.f * sa.y);
  const float cAz = rfl(-2.f * sa.z), cAw = rfl(-2.f * sa.w);
  const float s2A = rfl(fmaf(sa.x, sa.x, fmaf(sa.y, sa.y, fmaf(sa.z, sa.z, sa.w * sa.w))));
  const float cBx = rfl(-2.f * sb.x), cBy = rfl(-2.f * sb.y);
  const float cBz = rfl(-2.f * sb.z), cBw = rfl(-2.f * sb.w);
  const float s2B = rfl(fmaf(sb.x, sb.x, fmaf(sb.y, sb.y, fmaf(sb.z, sb.z, sb.w * sb.w))));

  unsigned* bufA = buf[2 * w];
  unsigned* bufB = buf[2 * w + 1];

  float thrA = __uint_as_float(0x7F800000u);   // +inf: accept everything at first
  float thrB = thrA;
  int cntA = 0, cntB = 0;

  for (int c = 0; c < 16; ++c) {
    __syncthreads();
    for (int t = tid; t < 1024; t += 512) {
      float4 p = s4[c * 1024 + t];
      spts[t] = p;
      s2s[t] = fmaf(p.x, p.x, fmaf(p.y, p.y, fmaf(p.z, p.z, p.w * p.w)));
    }
    __syncthreads();
    #pragma unroll 4
    for (int i = 0; i < 16; ++i) {
      int j = i * 64 + lane;
      float4 p = spts[j];
      float q = s2s[j];
      float dA = fmaf(cAx, p.x, fmaf(cAy, p.y, fmaf(cAz, p.z, fmaf(cAw, p.w, q + s2A))));
      float dB = fmaf(cBx, p.x, fmaf(cBy, p.y, fmaf(cBz, p.z, fmaf(cBw, p.w, q + s2B))));
      bool kA = dA <= thrA;
      unsigned long long mA = __ballot(kA);
      if (mA) {
        unsigned gi = (unsigned)((c << 10) + (i << 6) + lane);
        int pos = cntA + (int)mbcnt64(mA);
        if (kA) bufA[pos] = (__float_as_uint(fmaxf(dA, 0.f)) & 0xFFFFC000u) | gi;
        cntA += (int)__popcll(mA);
        if (cntA >= KNN_CAP - 64) {        // pre-iter cnt <= 383 -> never overflows
          CompactRes r = compact_buf(bufA, cntA, lane);
          cntA = r.cnt;
          thrA = __uint_as_float((r.thr & 0xFFFFC000u) | 0x3FFFu);
        }
      }
      bool kB = dB <= thrB;
      unsigned long long mB = __ballot(kB);
      if (mB) {
        unsigned gi = (unsigned)((c << 10) + (i << 6) + lane);
        int pos = cntB + (int)mbcnt64(mB);
        if (kB) bufB[pos] = (__float_as_uint(fmaxf(dB, 0.f)) & 0xFFFFC000u) | gi;
        cntB += (int)__popcll(mB);
        if (cntB >= KNN_CAP - 64) {
          CompactRes r = compact_buf(bufB, cntB, lane);
          cntB = r.cnt;
          thrB = __uint_as_float((r.thr & 0xFFFFC000u) | 0x3FFFu);
        }
      }
    }
  }

  if (cntA > 128) { CompactRes r = compact_buf(bufA, cntA, lane); cntA = r.cnt; }
  if (cntB > 128) { CompactRes r = compact_buf(bufB, cntB, lane); cntB = r.cnt; }

  // ---- finalists: exact d2 recompute + bitonic-128 sort + emit top-40 ----
  #pragma unroll
  for (int rr = 0; rr < 2; ++rr) {
    unsigned* bufR = rr ? bufB : bufA;
    int m = rr ? cntB : cntA;
    const float cx = rr ? cBx : cAx, cy = rr ? cBy : cAy;
    const float cz = rr ? cBz : cAz, cw = rr ? cBw : cAw;
    const float s2i = rr ? s2B : s2A;
    const int row = rr ? rB : rA;

    unsigned long long e0 = ~0ull, e1 = ~0ull;
    {
      int sl0 = lane * 2, sl1 = lane * 2 + 1;
      if (sl0 < m) {
        unsigned key = bufR[sl0];
        unsigned idx = key & 0x3FFFu;
        float4 p = s4[idx];
        float qj = fmaf(p.x, p.x, fmaf(p.y, p.y, fmaf(p.z, p.z, p.w * p.w)));
        float d = fmaf(cx, p.x, fmaf(cy, p.y, fmaf(cz, p.z, fmaf(cw, p.w, qj + s2i))));
        e0 = (((unsigned long long)__float_as_uint(fmaxf(d, 0.f))) << 32) | idx;
      }
      if (sl1 < m) {
        unsigned key = bufR[sl1];
        unsigned idx = key & 0x3FFFu;
        float4 p = s4[idx];
        float qj = fmaf(p.x, p.x, fmaf(p.y, p.y, fmaf(p.z, p.z, p.w * p.w)));
        float d = fmaf(cx, p.x, fmaf(cy, p.y, fmaf(cz, p.z, fmaf(cw, p.w, qj + s2i))));
        e1 = (((unsigned long long)__float_as_uint(fmaxf(d, 0.f))) << 32) | idx;
      }
    }

    #pragma unroll
    for (int k = 2; k <= 128; k <<= 1) {
      #pragma unroll
      for (int jj = k >> 1; jj >= 1; jj >>= 1) {
        bool up = (((lane * 2) & k) == 0);
        if (jj == 1) {
          unsigned long long a = (e0 < e1) ? e0 : e1;
          unsigned long long b = (e0 < e1) ? e1 : e0;
          e0 = up ? a : b; e1 = up ? b : a;
        } else {
          int lj = jj >> 1;
          bool lower = ((lane & lj) == 0);
          bool tm = (up == lower);
          unsigned long long o0 = __shfl_xor(e0, lj, 64);
          e0 = tm ? ((e0 < o0) ? e0 : o0) : ((e0 > o0) ? e0 : o0);
          unsigned long long o1 = __shfl_xor(e1, lj, 64);
          e1 = tm ? ((e1 < o1) ? e1 : o1) : ((e1 > o1) ? e1 : o1);
        }
      }
    }

    const int ob = row * KNN_K;
    if (lane < 20) {
      int v0 = lane * 2;
      idx_out[ob + v0] = (unsigned short)(e0 & 0xFFFFu);
      w_out[ob + v0] = f2bf(__expf(-10.f * __uint_as_float((unsigned)(e0 >> 32))));
      int v1 = v0 + 1;
      idx_out[ob + v1] = (unsigned short)(e1 & 0xFFFFu);
      w_out[ob + v1] = f2bf(__expf(-10.f * __uint_as_float((unsigned)(e1 >> 32))));
    }
  }
}

// ---------------------------------------------------------------------------
// Aggregation: Aout[i] = [mean_k h[idx]*w | max_k h[idx]*w]  (N x 128, bf16).
// ---------------------------------------------------------------------------
__global__ __launch_bounds__(256, 4) void agg_k(
    const unsigned short* __restrict__ h, const unsigned short* __restrict__ idxb,
    const unsigned short* __restrict__ wb, unsigned short* __restrict__ Aout)
{
  const int row = blockIdx.x * 4 + (threadIdx.x >> 6);
  const int lane = threadIdx.x & 63;
  const int base = row * KNN_K;
  float mean = 0.f, mx = -INFINITY;
  #pragma unroll 4
  for (int k = 0; k < KNN_K; ++k) {
    int j = idxb[base + k];
    float wv = bf2f(wb[base + k]);
    float m = bf2f(h[(size_t)j * 64 + lane]) * wv;
    mean += m;
    mx = fmaxf(mx, m);
  }
  Aout[(size_t)row * 128 + lane] = f2bf(mean * (1.f / 40.f));
  Aout[(size_t)row * 128 + 64 + lane] = f2bf(mx);
}

// ---------------------------------------------------------------------------
extern "C" void kernel_launch(void* const* d_in, const int* in_sizes, int n_in,
                              void* d_out, int out_size, void* d_ws, size_t ws_size,
                              hipStream_t stream)
{
  const float* x    = (const float*)d_in[0];
  const float* fc1W = (const float*)d_in[1];  const float* fc1b = (const float*)d_in[2];
  const float* fc2W = (const float*)d_in[3];  const float* fc2b = (const float*)d_in[4];
  const float* gsW  = (const float*)d_in[5];  const float* gsb  = (const float*)d_in[6];
  const float* ghW  = (const float*)d_in[7];  const float* ghb  = (const float*)d_in[8];
  const float* goW  = (const float*)d_in[9];  const float* gob  = (const float*)d_in[10];
  const float* d1W  = (const float*)d_in[11]; const float* d1b  = (const float*)d_in[12];
  const float* d2W  = (const float*)d_in[13]; const float* d2b  = (const float*)d_in[14];
  const float* d3W  = (const float*)d_in[15]; const float* d3b  = (const float*)d_in[16];
  const float* fc3W = (const float*)d_in[17]; const float* fc3b = (const float*)d_in[18];
  const float* fc4W = (const float*)d_in[19]; const float* fc4b = (const float*)d_in[20];
  float* out = (float*)d_out;

  // ---- workspace layout: ~14.5 MiB (bf16 activations, u16 idx) ----
  const size_t N = NPTS;
  u16* X    = (u16*)d_ws;
  u16* Abuf = X + N * 128;
  u16* T    = Abuf + N * 128;
  u16* IDX  = T + N * 128;
  u16* WNB  = IDX + N * 40;
  float* S = (float*)Abuf;        // N*4 fp32 aliased at start of Abuf
  u16* H = T;                     // N*64 bf16 aliased at start of T

  gemm_k<128, true, float, u16><<<NPTS / 64, 256, 0, stream>>>(
      x, 9, x, 9, 9, fc1W, fc1b, T, 128, 9);
  gemm_mfma_k<128, true><<<NPTS / 64, 256, 0, stream>>>(
      T, 128, T, 128, 128, fc2W, fc2b, X, 128, 128);

  for (int l = 0; l < 4; ++l) {
    gemm4_k<false, float><<<NPTS / 256, 256, 0, stream>>>(
        X, 128, gsW + l * 128 * 4, gsb + l * 4, S, 128);
    gemm_mfma_k<64, false><<<NPTS / 64, 256, 0, stream>>>(
        X, 128, X, 128, 128, ghW + l * 128 * 64, ghb + l * 64, H, 64, 128);
    knn_k<<<NPTS / 16, 512, 0, stream>>>(S, IDX, WNB);
    agg_k<<<NPTS / 4, 256, 0, stream>>>(H, IDX, WNB, Abuf);
    gemm_mfma_k<128, false><<<NPTS / 64, 256, 0, stream>>>(
        X, 128, Abuf, 128, 128, goW + l * 256 * 128, gob + l * 128, T, 128, 256);
    gemm_mfma_k<128, true><<<NPTS / 64, 256, 0, stream>>>(
        T, 128, T, 128, 128, d1W + l * 128 * 128, d1b + l * 128, Abuf, 128, 128);
    gemm_mfma_k<128, true><<<NPTS / 64, 256, 0, stream>>>(
        Abuf, 128, Abuf, 128, 128, d2W + l * 128 * 128, d2b + l * 128, T, 128, 128);
    gemm_mfma_k<128, true><<<NPTS / 64, 256, 0, stream>>>(
        T, 128, T, 128, 128, d3W + l * 128 * 128, d3b + l * 128, X, 128, 128);
  }

  gemm_mfma_k<128, true><<<NPTS / 64, 256, 0, stream>>>(
      X, 128, X, 128, 128, fc3W, fc3b, T, 128, 128);
  gemm4_k<false, float><<<NPTS / 256, 256, 0, stream>>>(
      T, 128, fc4W, fc4b, out, 128);
}